// Round 1
// baseline (625.411 us; speedup 1.0000x reference)
//
#include <hip/hip_runtime.h>

// GCN 3-layer, N=100000 nodes, E=800000 edges.
// out = A_hat @ (relu(A_hat @ (relu((A_hat @ x) @ W1 + b1)) @ W2 + b2) @ W3) + b3
// with A_hat = D^-1/2 (A + I) D^-1/2, weighted, deg over dst.
// Layer 1 aggregate-first (4 f/edge), layers 2-3 transform-first (64 / 1 f/edge).

constexpr int N = 100000;
constexpr int E = 800000;

static inline int cdiv(int a, int b) { return (a + b - 1) / b; }

__global__ void k_init_deg(float* __restrict__ deg) {
    int i = blockIdx.x * blockDim.x + threadIdx.x;
    if (i < N) deg[i] = 1.0f;  // self-loop weight
}

__global__ void k_deg_scatter(const int* __restrict__ dst, const float* __restrict__ w,
                              float* __restrict__ deg) {
    int i = blockIdx.x * blockDim.x + threadIdx.x;
    if (i < E) atomicAdd(&deg[dst[i]], w[i]);
}

__global__ void k_dis(float* __restrict__ deg) {
    int i = blockIdx.x * blockDim.x + threadIdx.x;
    if (i < N) {
        float d = deg[i];
        deg[i] = (d > 0.f) ? rsqrtf(fmaxf(d, 1e-12f)) : 0.f;
    }
}

__global__ void k_norm(const int* __restrict__ src, const int* __restrict__ dst,
                       const float* __restrict__ w, const float* __restrict__ dis,
                       float* __restrict__ nrm) {
    int i = blockIdx.x * blockDim.x + threadIdx.x;
    if (i < E) nrm[i] = dis[src[i]] * w[i] * dis[dst[i]];
}

// agg1[n] = dis[n]^2 * x[n]   (self-loop term of A_hat @ x)
__global__ void k_init_agg1(const float4* __restrict__ x, const float* __restrict__ dis,
                            float4* __restrict__ agg1) {
    int i = blockIdx.x * blockDim.x + threadIdx.x;
    if (i < N) {
        float d = dis[i], sc = d * d;
        float4 v = x[i];
        v.x *= sc; v.y *= sc; v.z *= sc; v.w *= sc;
        agg1[i] = v;
    }
}

__global__ void k_scatter1(const int* __restrict__ src, const int* __restrict__ dst,
                           const float* __restrict__ nrm, const float4* __restrict__ x,
                           float* __restrict__ agg1) {
    int i = blockIdx.x * blockDim.x + threadIdx.x;
    if (i < E) {
        int s = src[i], d = dst[i];
        float nm = nrm[i];
        float4 v = x[s];
        atomicAdd(&agg1[d * 4 + 0], nm * v.x);
        atomicAdd(&agg1[d * 4 + 1], nm * v.y);
        atomicAdd(&agg1[d * 4 + 2], nm * v.z);
        atomicAdd(&agg1[d * 4 + 3], nm * v.w);
    }
}

// y2[n,:] = relu(agg1[n,:] @ W1 + b1) @ W2   — h1 (128) staged per-wave in LDS,
// W2 (128x64, 32 KiB) staged per-block in LDS. One wave per node, 4 nodes/block.
__global__ __launch_bounds__(256) void k_fused_l1(const float4* __restrict__ agg1,
                                                  const float* __restrict__ W1,
                                                  const float* __restrict__ b1,
                                                  const float* __restrict__ W2,
                                                  float* __restrict__ y2) {
    __shared__ float sW2[128 * 64];
    __shared__ float sh1[4][128];
    int t = threadIdx.x;
    for (int i = t; i < 128 * 64; i += 256) sW2[i] = W2[i];
    int wave = t >> 6, lane = t & 63;
    int n = blockIdx.x * 4 + wave;
    if (n < N) {
        float4 a = agg1[n];
#pragma unroll
        for (int r = 0; r < 2; r++) {
            int k = lane * 2 + r;
            float v = b1[k];
            v = fmaf(a.x, W1[0 * 128 + k], v);
            v = fmaf(a.y, W1[1 * 128 + k], v);
            v = fmaf(a.z, W1[2 * 128 + k], v);
            v = fmaf(a.w, W1[3 * 128 + k], v);
            sh1[wave][k] = fmaxf(v, 0.f);
        }
    }
    __syncthreads();
    if (n < N) {
        float acc = 0.f;
#pragma unroll 8
        for (int k = 0; k < 128; k++)
            acc = fmaf(sh1[wave][k], sW2[k * 64 + lane], acc);  // sh1 broadcast; sW2 2-way (free)
        y2[n * 64 + lane] = acc;
    }
}

// agg2[n,j] = dis[n]^2 * y2[n,j]   (self-loop term)
__global__ void k_init_agg2(const float* __restrict__ dis, const float* __restrict__ y2,
                            float* __restrict__ agg2) {
    int gid = blockIdx.x * blockDim.x + threadIdx.x;
    if (gid < N * 64) {
        int n = gid >> 6;
        float d = dis[n];
        agg2[gid] = d * d * y2[gid];
    }
}

// one wave per edge: lane j handles feature j. src/dst/nrm loads are wave-uniform (broadcast).
__global__ void k_scatter2(const int* __restrict__ src, const int* __restrict__ dst,
                           const float* __restrict__ nrm, const float* __restrict__ y2,
                           float* __restrict__ agg2) {
    int gid = blockIdx.x * blockDim.x + threadIdx.x;  // E*64 = 51.2M, exact multiple of 256
    int e = gid >> 6, j = gid & 63;
    int s = src[e], d = dst[e];
    float nm = nrm[e];
    atomicAdd(&agg2[d * 64 + j], nm * y2[s * 64 + j]);
}

// s[n] = relu(agg2[n,:]+b2) @ W3 ; out[n] = dis[n]^2 * s[n] + b3  (self-loop of layer 3)
__global__ __launch_bounds__(256) void k_l2_tail(const float* __restrict__ agg2,
                                                 const float* __restrict__ b2,
                                                 const float* __restrict__ W3,
                                                 const float* __restrict__ b3,
                                                 const float* __restrict__ dis,
                                                 float* __restrict__ s_out,
                                                 float* __restrict__ out) {
    int t = threadIdx.x, wave = t >> 6, lane = t & 63;
    int n = blockIdx.x * 4 + wave;
    if (n >= N) return;
    float h = fmaxf(agg2[n * 64 + lane] + b2[lane], 0.f);
    float p = h * W3[lane];
#pragma unroll
    for (int off = 32; off > 0; off >>= 1) p += __shfl_down(p, off);
    if (lane == 0) {
        s_out[n] = p;
        float d = dis[n];
        out[n] = d * d * p + b3[0];
    }
}

__global__ void k_scatter3(const int* __restrict__ src, const int* __restrict__ dst,
                           const float* __restrict__ nrm, const float* __restrict__ s,
                           float* __restrict__ out) {
    int i = blockIdx.x * blockDim.x + threadIdx.x;
    if (i < E) atomicAdd(&out[dst[i]], nrm[i] * s[src[i]]);
}

extern "C" void kernel_launch(void* const* d_in, const int* in_sizes, int n_in,
                              void* d_out, int out_size, void* d_ws, size_t ws_size,
                              hipStream_t stream) {
    const float* x  = (const float*)d_in[0];
    const int*   ei = (const int*)d_in[1];   // int32: JAX x64-disabled canonicalizes int64
    const int* src = ei;
    const int* dst = ei + E;
    const float* w  = (const float*)d_in[2];
    const float* W1 = (const float*)d_in[3];
    const float* b1 = (const float*)d_in[4];
    const float* W2 = (const float*)d_in[5];
    const float* b2 = (const float*)d_in[6];
    const float* W3 = (const float*)d_in[7];
    const float* b3 = (const float*)d_in[8];
    float* out = (float*)d_out;

    // workspace layout (floats): dis[N] | nrm[E] | agg1[4N] | y2[64N] | agg2[64N] | s[N]
    // total = 134N + E = 14.2M floats = 56.8 MB
    float* ws   = (float*)d_ws;
    float* dis  = ws;
    float* nrm  = dis + N;
    float* agg1 = nrm + E;
    float* y2   = agg1 + 4 * N;
    float* agg2 = y2 + 64 * N;
    float* s    = agg2 + 64 * N;

    k_init_deg   <<<cdiv(N, 256),      256, 0, stream>>>(dis);
    k_deg_scatter<<<cdiv(E, 256),      256, 0, stream>>>(dst, w, dis);
    k_dis        <<<cdiv(N, 256),      256, 0, stream>>>(dis);
    k_norm       <<<cdiv(E, 256),      256, 0, stream>>>(src, dst, w, dis, nrm);
    k_init_agg1  <<<cdiv(N, 256),      256, 0, stream>>>((const float4*)x, dis, (float4*)agg1);
    k_scatter1   <<<cdiv(E, 256),      256, 0, stream>>>(src, dst, nrm, (const float4*)x, agg1);
    k_fused_l1   <<<cdiv(N, 4),        256, 0, stream>>>((const float4*)agg1, W1, b1, W2, y2);
    k_init_agg2  <<<cdiv(N * 64, 256), 256, 0, stream>>>(dis, y2, agg2);
    k_scatter2   <<<E * 64 / 256,      256, 0, stream>>>(src, dst, nrm, y2, agg2);
    k_l2_tail    <<<cdiv(N, 4),        256, 0, stream>>>(agg2, b2, W3, b3, dis, s, out);
    k_scatter3   <<<cdiv(E, 256),      256, 0, stream>>>(src, dst, nrm, s, out);
}

// Round 2
// 366.849 us; speedup vs baseline: 1.7048x; 1.7048x over previous
//
#include <hip/hip_runtime.h>

// GCN 3-layer, N=100000 nodes, E=800000 edges, f32.
// out = A_hat @ (relu(A_hat @ (relu((A_hat @ x) @ W1 + b1)) @ W2 + b2) @ W3) + b3
// A_hat = D^-1/2 (A + I) D^-1/2, weighted, deg over dst.
//
// R1: atomic scatters replaced by per-launch CSR build (hist -> scan -> fill,
// edges bucketed by dst with permuted src/norm arrays) + gather-per-node
// aggregation. Layer-2 aggregation fused with bias/relu/W3-dot/self-loop.

constexpr int N = 100000;
constexpr int E = 800000;
constexpr int NB = (N + 255) / 256;  // 391 scan blocks

static inline int cdiv(int a, int b) { return (a + b - 1) / b; }

// ---- CSR build ----------------------------------------------------------

__global__ void k_init(int* __restrict__ cnt, float* __restrict__ deg) {
    int i = blockIdx.x * blockDim.x + threadIdx.x;
    if (i < N) { cnt[i] = 0; deg[i] = 1.0f; }  // self-loop weight 1
}

__global__ void k_hist(const int* __restrict__ dst, const float* __restrict__ w,
                       int* __restrict__ cnt, float* __restrict__ deg) {
    int i = blockIdx.x * blockDim.x + threadIdx.x;
    if (i < E) {
        int d = dst[i];
        atomicAdd(&cnt[d], 1);
        atomicAdd(&deg[d], w[i]);
    }
}

__global__ void k_scan_block(const int* __restrict__ cnt, int* __restrict__ excl,
                             int* __restrict__ bsum) {
    __shared__ int tmp[256];
    int t = threadIdx.x, g = blockIdx.x * 256 + t;
    int v = (g < N) ? cnt[g] : 0;
    tmp[t] = v;
    __syncthreads();
    for (int off = 1; off < 256; off <<= 1) {
        int u = (t >= off) ? tmp[t - off] : 0;
        __syncthreads();
        tmp[t] += u;
        __syncthreads();
    }
    if (g < N) excl[g] = tmp[t] - v;
    if (t == 255) bsum[blockIdx.x] = tmp[255];
}

__global__ void k_scan_tops(int* __restrict__ bsum) {  // in-place exclusive, NB<=512
    __shared__ int tmp[512];
    int t = threadIdx.x;
    int v = (t < NB) ? bsum[t] : 0;
    tmp[t] = v;
    __syncthreads();
    for (int off = 1; off < 512; off <<= 1) {
        int u = (t >= off) ? tmp[t - off] : 0;
        __syncthreads();
        tmp[t] += u;
        __syncthreads();
    }
    if (t < NB) bsum[t] = tmp[t] - v;
}

__global__ void k_finalize(const int* __restrict__ excl, const int* __restrict__ bsum,
                           const float* __restrict__ deg, int* __restrict__ row_start,
                           int* __restrict__ cursor, float* __restrict__ dis) {
    int n = blockIdx.x * blockDim.x + threadIdx.x;
    if (n < N) {
        int rs = excl[n] + bsum[n >> 8];
        row_start[n] = rs;
        cursor[n] = rs;
        dis[n] = rsqrtf(deg[n]);  // deg >= 1 always (self loop)
    }
}

// bucket edges by dst; store src and norm in permuted (dst-sorted) order
__global__ void k_fill(const int* __restrict__ src, const int* __restrict__ dst,
                       const float* __restrict__ w, const float* __restrict__ dis,
                       int* __restrict__ cursor, int* __restrict__ esrc_p,
                       float* __restrict__ enrm_p) {
    int i = blockIdx.x * blockDim.x + threadIdx.x;
    if (i < E) {
        int s = src[i], d = dst[i];
        float nm = dis[s] * w[i] * dis[d];
        int pos = atomicAdd(&cursor[d], 1);
        esrc_p[pos] = s;
        enrm_p[pos] = nm;
    }
}

// ---- layer 1: aggregate-first (4 floats/node), thread per node ----------

__global__ void k_agg1(const float4* __restrict__ x, const float* __restrict__ dis,
                       const int* __restrict__ row_start, const int* __restrict__ cnt,
                       const int* __restrict__ esrc_p, const float* __restrict__ enrm_p,
                       float4* __restrict__ agg1) {
    int n = blockIdx.x * blockDim.x + threadIdx.x;
    if (n >= N) return;
    float di = dis[n], sc = di * di;
    float4 v = x[n];
    float ax = sc * v.x, ay = sc * v.y, az = sc * v.z, aw = sc * v.w;
    int beg = row_start[n], end = beg + cnt[n];
    for (int e = beg; e < end; e++) {
        float nm = enrm_p[e];
        float4 u = x[esrc_p[e]];
        ax = fmaf(nm, u.x, ax); ay = fmaf(nm, u.y, ay);
        az = fmaf(nm, u.z, az); aw = fmaf(nm, u.w, aw);
    }
    agg1[n] = make_float4(ax, ay, az, aw);
}

// y2[n,:] = relu(agg1[n,:] @ W1 + b1) @ W2 — W2 staged once per block (32 nodes)
__global__ __launch_bounds__(256) void k_fused_l1(const float4* __restrict__ agg1,
                                                  const float* __restrict__ W1,
                                                  const float* __restrict__ b1,
                                                  const float* __restrict__ W2,
                                                  float* __restrict__ y2) {
    __shared__ float sW2[128 * 64];
    __shared__ float sh1[4][128];
    int t = threadIdx.x;
    for (int i = t; i < 128 * 64; i += 256) sW2[i] = W2[i];
    int wave = t >> 6, lane = t & 63;
    __syncthreads();
    for (int g = 0; g < 8; g++) {
        int n = blockIdx.x * 32 + g * 4 + wave;
        if (n < N) {
            float4 a = agg1[n];
#pragma unroll
            for (int r = 0; r < 2; r++) {
                int k = lane * 2 + r;
                float v = b1[k];
                v = fmaf(a.x, W1[0 * 128 + k], v);
                v = fmaf(a.y, W1[1 * 128 + k], v);
                v = fmaf(a.z, W1[2 * 128 + k], v);
                v = fmaf(a.w, W1[3 * 128 + k], v);
                sh1[wave][k] = fmaxf(v, 0.f);  // wave-local LDS: no block barrier needed
            }
            float acc = 0.f;
#pragma unroll 8
            for (int k = 0; k < 128; k++)
                acc = fmaf(sh1[wave][k], sW2[k * 64 + lane], acc);
            y2[(size_t)n * 64 + lane] = acc;
        }
    }
}

// ---- layer 2 aggregate + bias/relu + W3 dot + layer-3 self-loop, wave/node
__global__ __launch_bounds__(256) void k_agg2_fused(
        const float* __restrict__ y2, const float* __restrict__ dis,
        const int* __restrict__ row_start, const int* __restrict__ cnt,
        const int* __restrict__ esrc_p, const float* __restrict__ enrm_p,
        const float* __restrict__ b2, const float* __restrict__ W3,
        const float* __restrict__ b3, float* __restrict__ s_out,
        float* __restrict__ out) {
    int t = threadIdx.x, wave = t >> 6, lane = t & 63;
    int n = blockIdx.x * 4 + wave;
    if (n >= N) return;
    float di = dis[n];
    float acc = di * di * y2[(size_t)n * 64 + lane];  // self-loop term
    int beg = row_start[n], end = beg + cnt[n];
    int e = beg;
    for (; e + 1 < end; e += 2) {  // 2-way unroll for outstanding loads
        int s0 = esrc_p[e], s1 = esrc_p[e + 1];
        float n0 = enrm_p[e], n1 = enrm_p[e + 1];
        float v0 = y2[(size_t)s0 * 64 + lane];
        float v1 = y2[(size_t)s1 * 64 + lane];
        acc = fmaf(n0, v0, acc);
        acc = fmaf(n1, v1, acc);
    }
    if (e < end) acc = fmaf(enrm_p[e], y2[(size_t)esrc_p[e] * 64 + lane], acc);
    float h = fmaxf(acc + b2[lane], 0.f);
    float p = h * W3[lane];
#pragma unroll
    for (int off = 32; off > 0; off >>= 1) p += __shfl_down(p, off);
    if (lane == 0) {
        s_out[n] = p;
        out[n] = di * di * p + b3[0];  // layer-3 self-loop + bias
    }
}

// ---- layer 3 aggregation: out[n] += sum nrm * s[src], thread per node ----

__global__ void k_agg3(const float* __restrict__ s, const int* __restrict__ row_start,
                       const int* __restrict__ cnt, const int* __restrict__ esrc_p,
                       const float* __restrict__ enrm_p, float* __restrict__ out) {
    int n = blockIdx.x * blockDim.x + threadIdx.x;
    if (n >= N) return;
    float acc = 0.f;
    int beg = row_start[n], end = beg + cnt[n];
    for (int e = beg; e < end; e++)
        acc = fmaf(enrm_p[e], s[esrc_p[e]], acc);
    out[n] += acc;
}

extern "C" void kernel_launch(void* const* d_in, const int* in_sizes, int n_in,
                              void* d_out, int out_size, void* d_ws, size_t ws_size,
                              hipStream_t stream) {
    const float* x  = (const float*)d_in[0];
    const int*   ei = (const int*)d_in[1];   // int32 (JAX x64-disabled)
    const int* src = ei;
    const int* dst = ei + E;
    const float* w  = (const float*)d_in[2];
    const float* W1 = (const float*)d_in[3];
    const float* b1 = (const float*)d_in[4];
    const float* W2 = (const float*)d_in[5];
    const float* b2 = (const float*)d_in[6];
    const float* W3 = (const float*)d_in[7];
    const float* b3 = (const float*)d_in[8];
    float* out = (float*)d_out;

    // ws layout (all 4B elems): ints then floats, ~36 MB total
    int*   cnt       = (int*)d_ws;
    int*   excl      = cnt + N;
    int*   bsum      = excl + N;         // 512
    int*   row_start = bsum + 512;
    int*   cursor    = row_start + N;
    int*   esrc_p    = cursor + N;       // E
    float* deg       = (float*)(esrc_p + E);  // doubles as dis after finalize
    float* enrm_p    = deg + N;          // E
    float* agg1      = enrm_p + E;       // 4N
    float* y2        = agg1 + 4 * N;     // 64N
    float* s         = y2 + (size_t)64 * N;  // N
    float* dis       = deg;

    k_init      <<<cdiv(N, 256), 256, 0, stream>>>(cnt, deg);
    k_hist      <<<cdiv(E, 256), 256, 0, stream>>>(dst, w, cnt, deg);
    k_scan_block<<<NB,           256, 0, stream>>>(cnt, excl, bsum);
    k_scan_tops <<<1,            512, 0, stream>>>(bsum);
    k_finalize  <<<cdiv(N, 256), 256, 0, stream>>>(excl, bsum, deg, row_start, cursor, dis);
    k_fill      <<<cdiv(E, 256), 256, 0, stream>>>(src, dst, w, dis, cursor, esrc_p, enrm_p);
    k_agg1      <<<cdiv(N, 256), 256, 0, stream>>>((const float4*)x, dis, row_start, cnt,
                                                   esrc_p, enrm_p, (float4*)agg1);
    k_fused_l1  <<<N / 32,       256, 0, stream>>>((const float4*)agg1, W1, b1, W2, y2);
    k_agg2_fused<<<cdiv(N, 4),   256, 0, stream>>>(y2, dis, row_start, cnt, esrc_p, enrm_p,
                                                   b2, W3, b3, s, out);
    k_agg3      <<<cdiv(N, 256), 256, 0, stream>>>(s, row_start, cnt, esrc_p, enrm_p, out);
}

// Round 3
// 336.024 us; speedup vs baseline: 1.8612x; 1.0917x over previous
//
#include <hip/hip_runtime.h>

// GCN 3-layer, N=100000 nodes, E=800000 edges, f32.
// out = A_hat @ (relu(A_hat @ (relu((A_hat @ x) @ W1 + b1)) @ W2 + b2) @ W3) + b3
// A_hat = D^-1/2 (A + I) D^-1/2, weighted, deg over dst.
//
// R1: CSR build (hist -> scan -> fill) + gather-per-node aggregation, no big atomics.
// R2: k_fused_l1 register-blocked: 8 nodes/wave, h1 k-major stride-12 in LDS,
//     inner loop = 3 LDS reads per 8 FMAs (was 2 LDS reads per 1 FMA).

constexpr int N = 100000;
constexpr int E = 800000;
constexpr int NB = (N + 255) / 256;  // 391 scan blocks

static inline int cdiv(int a, int b) { return (a + b - 1) / b; }

// ---- CSR build ----------------------------------------------------------

__global__ void k_init(int* __restrict__ cnt, float* __restrict__ deg) {
    int i = blockIdx.x * blockDim.x + threadIdx.x;
    if (i < N) { cnt[i] = 0; deg[i] = 1.0f; }  // self-loop weight 1
}

__global__ void k_hist(const int* __restrict__ dst, const float* __restrict__ w,
                       int* __restrict__ cnt, float* __restrict__ deg) {
    int i = blockIdx.x * blockDim.x + threadIdx.x;
    if (i < E) {
        int d = dst[i];
        atomicAdd(&cnt[d], 1);
        atomicAdd(&deg[d], w[i]);
    }
}

__global__ void k_scan_block(const int* __restrict__ cnt, int* __restrict__ excl,
                             int* __restrict__ bsum) {
    __shared__ int tmp[256];
    int t = threadIdx.x, g = blockIdx.x * 256 + t;
    int v = (g < N) ? cnt[g] : 0;
    tmp[t] = v;
    __syncthreads();
    for (int off = 1; off < 256; off <<= 1) {
        int u = (t >= off) ? tmp[t - off] : 0;
        __syncthreads();
        tmp[t] += u;
        __syncthreads();
    }
    if (g < N) excl[g] = tmp[t] - v;
    if (t == 255) bsum[blockIdx.x] = tmp[255];
}

__global__ void k_scan_tops(int* __restrict__ bsum) {  // in-place exclusive, NB<=512
    __shared__ int tmp[512];
    int t = threadIdx.x;
    int v = (t < NB) ? bsum[t] : 0;
    tmp[t] = v;
    __syncthreads();
    for (int off = 1; off < 512; off <<= 1) {
        int u = (t >= off) ? tmp[t - off] : 0;
        __syncthreads();
        tmp[t] += u;
        __syncthreads();
    }
    if (t < NB) bsum[t] = tmp[t] - v;
}

__global__ void k_finalize(const int* __restrict__ excl, const int* __restrict__ bsum,
                           const float* __restrict__ deg, int* __restrict__ row_start,
                           int* __restrict__ cursor, float* __restrict__ dis) {
    int n = blockIdx.x * blockDim.x + threadIdx.x;
    if (n < N) {
        int rs = excl[n] + bsum[n >> 8];
        row_start[n] = rs;
        cursor[n] = rs;
        dis[n] = rsqrtf(deg[n]);  // deg >= 1 always (self loop)
    }
}

// bucket edges by dst; store src and norm in permuted (dst-sorted) order
__global__ void k_fill(const int* __restrict__ src, const int* __restrict__ dst,
                       const float* __restrict__ w, const float* __restrict__ dis,
                       int* __restrict__ cursor, int* __restrict__ esrc_p,
                       float* __restrict__ enrm_p) {
    int i = blockIdx.x * blockDim.x + threadIdx.x;
    if (i < E) {
        int s = src[i], d = dst[i];
        float nm = dis[s] * w[i] * dis[d];
        int pos = atomicAdd(&cursor[d], 1);
        esrc_p[pos] = s;
        enrm_p[pos] = nm;
    }
}

// ---- layer 1: aggregate-first (4 floats/node), thread per node ----------

__global__ void k_agg1(const float4* __restrict__ x, const float* __restrict__ dis,
                       const int* __restrict__ row_start, const int* __restrict__ cnt,
                       const int* __restrict__ esrc_p, const float* __restrict__ enrm_p,
                       float4* __restrict__ agg1) {
    int n = blockIdx.x * blockDim.x + threadIdx.x;
    if (n >= N) return;
    float di = dis[n], sc = di * di;
    float4 v = x[n];
    float ax = sc * v.x, ay = sc * v.y, az = sc * v.z, aw = sc * v.w;
    int beg = row_start[n], end = beg + cnt[n];
    for (int e = beg; e < end; e++) {
        float nm = enrm_p[e];
        float4 u = x[esrc_p[e]];
        ax = fmaf(nm, u.x, ax); ay = fmaf(nm, u.y, ay);
        az = fmaf(nm, u.z, az); aw = fmaf(nm, u.w, aw);
    }
    agg1[n] = make_float4(ax, ay, az, aw);
}

// ---- y2[n,:] = relu(agg1[n,:] @ W1 + b1) @ W2 ---------------------------
// R2: 8 nodes/wave register-blocked. sh1 per-wave, k-major, stride 12
// (16B-aligned b128 reads; writes land on 8 banks but only 4 instrs/group).
// Inner loop per k: 1 ds_read_b32 (W2) + 2 broadcast ds_read_b128 (h1) + 8 FMA.
constexpr int HSTR = 12;  // sh1 row stride (dwords) for 8 nodes
__global__ __launch_bounds__(256) void k_fused_l1(const float4* __restrict__ agg1,
                                                  const float* __restrict__ W1,
                                                  const float* __restrict__ b1,
                                                  const float* __restrict__ W2,
                                                  float* __restrict__ y2) {
    __shared__ float sW2[128 * 64];            // 32 KB
    __shared__ float sh1[4][128 * HSTR];       // 4 waves x 6 KB
    int t = threadIdx.x;
    for (int i = t; i < 128 * 64; i += 256) sW2[i] = W2[i];
    int wave = t >> 6, lane = t & 63;
    float* sh = sh1[wave];
    __syncthreads();

#pragma unroll
    for (int g = 0; g < 2; g++) {
        int n0 = blockIdx.x * 64 + wave * 16 + g * 8;  // 8 nodes for this wave
        // Phase A: h1[k][m] = relu(b1[k] + agg1[n0+m] . W1[:,k]), lane = k (2 halves)
#pragma unroll
        for (int r = 0; r < 2; r++) {
            int k = r * 64 + lane;
            float w0 = W1[0 * 128 + k], w1 = W1[1 * 128 + k];
            float w2 = W1[2 * 128 + k], w3 = W1[3 * 128 + k];
            float bb = b1[k];
            float hv[8];
#pragma unroll
            for (int m = 0; m < 8; m++) {
                int nn = n0 + m; if (nn >= N) nn = N - 1;  // clamp (dup, stores guarded)
                float4 a = agg1[nn];
                float v = bb;
                v = fmaf(a.x, w0, v); v = fmaf(a.y, w1, v);
                v = fmaf(a.z, w2, v); v = fmaf(a.w, w3, v);
                hv[m] = fmaxf(v, 0.f);
            }
            *(float4*)&sh[k * HSTR + 0] = make_float4(hv[0], hv[1], hv[2], hv[3]);
            *(float4*)&sh[k * HSTR + 4] = make_float4(hv[4], hv[5], hv[6], hv[7]);
        }
        // Phase B: acc[m] += h1[k][m] * W2[k][lane]  (wave-local LDS, no barrier)
        float acc[8] = {0.f, 0.f, 0.f, 0.f, 0.f, 0.f, 0.f, 0.f};
        for (int k = 0; k < 128; k++) {
            float w2v = sW2[k * 64 + lane];
            float4 h03 = *(const float4*)&sh[k * HSTR + 0];
            float4 h47 = *(const float4*)&sh[k * HSTR + 4];
            acc[0] = fmaf(h03.x, w2v, acc[0]);
            acc[1] = fmaf(h03.y, w2v, acc[1]);
            acc[2] = fmaf(h03.z, w2v, acc[2]);
            acc[3] = fmaf(h03.w, w2v, acc[3]);
            acc[4] = fmaf(h47.x, w2v, acc[4]);
            acc[5] = fmaf(h47.y, w2v, acc[5]);
            acc[6] = fmaf(h47.z, w2v, acc[6]);
            acc[7] = fmaf(h47.w, w2v, acc[7]);
        }
#pragma unroll
        for (int m = 0; m < 8; m++) {
            int nn = n0 + m;
            if (nn < N) y2[(size_t)nn * 64 + lane] = acc[m];
        }
    }
}

// ---- layer 2 aggregate + bias/relu + W3 dot + layer-3 self-loop, wave/node
__global__ __launch_bounds__(256) void k_agg2_fused(
        const float* __restrict__ y2, const float* __restrict__ dis,
        const int* __restrict__ row_start, const int* __restrict__ cnt,
        const int* __restrict__ esrc_p, const float* __restrict__ enrm_p,
        const float* __restrict__ b2, const float* __restrict__ W3,
        const float* __restrict__ b3, float* __restrict__ s_out,
        float* __restrict__ out) {
    int t = threadIdx.x, wave = t >> 6, lane = t & 63;
    int n = blockIdx.x * 4 + wave;
    if (n >= N) return;
    float di = dis[n];
    float acc = di * di * y2[(size_t)n * 64 + lane];  // self-loop term
    int beg = row_start[n], end = beg + cnt[n];
    int e = beg;
    for (; e + 1 < end; e += 2) {  // 2-way unroll for outstanding loads
        int s0 = esrc_p[e], s1 = esrc_p[e + 1];
        float n0 = enrm_p[e], n1 = enrm_p[e + 1];
        float v0 = y2[(size_t)s0 * 64 + lane];
        float v1 = y2[(size_t)s1 * 64 + lane];
        acc = fmaf(n0, v0, acc);
        acc = fmaf(n1, v1, acc);
    }
    if (e < end) acc = fmaf(enrm_p[e], y2[(size_t)esrc_p[e] * 64 + lane], acc);
    float h = fmaxf(acc + b2[lane], 0.f);
    float p = h * W3[lane];
#pragma unroll
    for (int off = 32; off > 0; off >>= 1) p += __shfl_down(p, off);
    if (lane == 0) {
        s_out[n] = p;
        out[n] = di * di * p + b3[0];  // layer-3 self-loop + bias
    }
}

// ---- layer 3 aggregation: out[n] += sum nrm * s[src], thread per node ----

__global__ void k_agg3(const float* __restrict__ s, const int* __restrict__ row_start,
                       const int* __restrict__ cnt, const int* __restrict__ esrc_p,
                       const float* __restrict__ enrm_p, float* __restrict__ out) {
    int n = blockIdx.x * blockDim.x + threadIdx.x;
    if (n >= N) return;
    float acc = 0.f;
    int beg = row_start[n], end = beg + cnt[n];
    for (int e = beg; e < end; e++)
        acc = fmaf(enrm_p[e], s[esrc_p[e]], acc);
    out[n] += acc;
}

extern "C" void kernel_launch(void* const* d_in, const int* in_sizes, int n_in,
                              void* d_out, int out_size, void* d_ws, size_t ws_size,
                              hipStream_t stream) {
    const float* x  = (const float*)d_in[0];
    const int*   ei = (const int*)d_in[1];   // int32 (JAX x64-disabled)
    const int* src = ei;
    const int* dst = ei + E;
    const float* w  = (const float*)d_in[2];
    const float* W1 = (const float*)d_in[3];
    const float* b1 = (const float*)d_in[4];
    const float* W2 = (const float*)d_in[5];
    const float* b2 = (const float*)d_in[6];
    const float* W3 = (const float*)d_in[7];
    const float* b3 = (const float*)d_in[8];
    float* out = (float*)d_out;

    // ws layout (all 4B elems): ints then floats, ~36 MB total
    int*   cnt       = (int*)d_ws;
    int*   excl      = cnt + N;
    int*   bsum      = excl + N;         // 512
    int*   row_start = bsum + 512;
    int*   cursor    = row_start + N;
    int*   esrc_p    = cursor + N;       // E
    float* deg       = (float*)(esrc_p + E);  // doubles as dis after finalize
    float* enrm_p    = deg + N;          // E
    float* agg1      = enrm_p + E;       // 4N
    float* y2        = agg1 + 4 * N;     // 64N
    float* s         = y2 + (size_t)64 * N;  // N
    float* dis       = deg;

    k_init      <<<cdiv(N, 256), 256, 0, stream>>>(cnt, deg);
    k_hist      <<<cdiv(E, 256), 256, 0, stream>>>(dst, w, cnt, deg);
    k_scan_block<<<NB,           256, 0, stream>>>(cnt, excl, bsum);
    k_scan_tops <<<1,            512, 0, stream>>>(bsum);
    k_finalize  <<<cdiv(N, 256), 256, 0, stream>>>(excl, bsum, deg, row_start, cursor, dis);
    k_fill      <<<cdiv(E, 256), 256, 0, stream>>>(src, dst, w, dis, cursor, esrc_p, enrm_p);
    k_agg1      <<<cdiv(N, 256), 256, 0, stream>>>((const float4*)x, dis, row_start, cnt,
                                                   esrc_p, enrm_p, (float4*)agg1);
    k_fused_l1  <<<cdiv(N, 64),  256, 0, stream>>>((const float4*)agg1, W1, b1, W2, y2);
    k_agg2_fused<<<cdiv(N, 4),   256, 0, stream>>>(y2, dis, row_start, cnt, esrc_p, enrm_p,
                                                   b2, W3, b3, s, out);
    k_agg3      <<<cdiv(N, 256), 256, 0, stream>>>(s, row_start, cnt, esrc_p, enrm_p, out);
}

// Round 4
// 265.743 us; speedup vs baseline: 2.3534x; 1.2645x over previous
//
#include <hip/hip_runtime.h>

// GCN 3-layer, N=100000 nodes, E=800000 edges, f32.
// out = A_hat @ (relu(A_hat @ (relu((A_hat @ x) @ W1 + b1)) @ W2 + b2) @ W3) + b3
// A_hat = D^-1/2 (A + I) D^-1/2, weighted, deg over dst.
//
// R1: CSR + gather (no big atomic scatters). R2: k_fused_l1 register-blocked.
// R3: hist/scan/finalize CSR build replaced by direct fixed-capacity bucketing:
//     one atomic + one 8B cached store per edge (device atomics write through
//     L2 at 32B/transaction — measured 50 MB WRITE_SIZE for 1.6M atomics — so
//     transaction count is the currency). deg/dis derived from buckets, norm
//     computed at use (dis is 400 KB, L2-resident).

constexpr int N = 100000;
constexpr int E = 800000;

static inline int cdiv(int a, int b) { return (a + b - 1) / b; }

__global__ void k_zero(int* __restrict__ cursor) {
    int i = blockIdx.x * blockDim.x + threadIdx.x;
    if (i < N) cursor[i] = 0;
}

// bucket edges by dst: payload[d*cap + pos] = {src, bits(w)}
__global__ void k_fill_direct(const int* __restrict__ src, const int* __restrict__ dst,
                              const float* __restrict__ w, int* __restrict__ cursor,
                              int2* __restrict__ payload, int cap) {
    int i = blockIdx.x * blockDim.x + threadIdx.x;
    if (i < E) {
        int d = dst[i];
        int pos = atomicAdd(&cursor[d], 1);
        if (pos < cap)
            payload[(size_t)d * cap + pos] = make_int2(src[i], __float_as_int(w[i]));
    }
}

// dis[n] = rsqrt(1 + sum w over row n); clamp stored count to cap
__global__ void k_deg_dis(int* __restrict__ cursor, const int2* __restrict__ payload,
                          int cap, float* __restrict__ dis) {
    int n = blockIdx.x * blockDim.x + threadIdx.x;
    if (n >= N) return;
    int c = cursor[n]; if (c > cap) { c = cap; cursor[n] = c; }
    const int2* row = payload + (size_t)n * cap;
    float sum = 1.0f;  // self-loop weight
    for (int e = 0; e < c; e++) sum += __int_as_float(row[e].y);
    dis[n] = rsqrtf(sum);
}

// ---- layer 1: aggregate-first (4 floats/node), thread per node ----------
__global__ void k_agg1(const float4* __restrict__ x, const float* __restrict__ dis,
                       const int* __restrict__ cursor, const int2* __restrict__ payload,
                       int cap, float4* __restrict__ agg1) {
    int n = blockIdx.x * blockDim.x + threadIdx.x;
    if (n >= N) return;
    float di = dis[n], sc = di * di;
    float4 v = x[n];
    float ax = sc * v.x, ay = sc * v.y, az = sc * v.z, aw = sc * v.w;
    int c = cursor[n];
    const int2* row = payload + (size_t)n * cap;
    for (int e = 0; e < c; e++) {
        int2 p = row[e];
        float nm = dis[p.x] * __int_as_float(p.y) * di;
        float4 u = x[p.x];
        ax = fmaf(nm, u.x, ax); ay = fmaf(nm, u.y, ay);
        az = fmaf(nm, u.z, az); aw = fmaf(nm, u.w, aw);
    }
    agg1[n] = make_float4(ax, ay, az, aw);
}

// ---- y2[n,:] = relu(agg1[n,:] @ W1 + b1) @ W2 (R2 register-blocked) -----
constexpr int HSTR = 12;
__global__ __launch_bounds__(256) void k_fused_l1(const float4* __restrict__ agg1,
                                                  const float* __restrict__ W1,
                                                  const float* __restrict__ b1,
                                                  const float* __restrict__ W2,
                                                  float* __restrict__ y2) {
    __shared__ float sW2[128 * 64];            // 32 KB
    __shared__ float sh1[4][128 * HSTR];       // 4 waves x 6 KB
    int t = threadIdx.x;
    for (int i = t; i < 128 * 64; i += 256) sW2[i] = W2[i];
    int wave = t >> 6, lane = t & 63;
    float* sh = sh1[wave];
    __syncthreads();

#pragma unroll
    for (int g = 0; g < 2; g++) {
        int n0 = blockIdx.x * 64 + wave * 16 + g * 8;
#pragma unroll
        for (int r = 0; r < 2; r++) {
            int k = r * 64 + lane;
            float w0 = W1[0 * 128 + k], w1 = W1[1 * 128 + k];
            float w2 = W1[2 * 128 + k], w3 = W1[3 * 128 + k];
            float bb = b1[k];
            float hv[8];
#pragma unroll
            for (int m = 0; m < 8; m++) {
                int nn = n0 + m; if (nn >= N) nn = N - 1;
                float4 a = agg1[nn];
                float v = bb;
                v = fmaf(a.x, w0, v); v = fmaf(a.y, w1, v);
                v = fmaf(a.z, w2, v); v = fmaf(a.w, w3, v);
                hv[m] = fmaxf(v, 0.f);
            }
            *(float4*)&sh[k * HSTR + 0] = make_float4(hv[0], hv[1], hv[2], hv[3]);
            *(float4*)&sh[k * HSTR + 4] = make_float4(hv[4], hv[5], hv[6], hv[7]);
        }
        float acc[8] = {0.f, 0.f, 0.f, 0.f, 0.f, 0.f, 0.f, 0.f};
        for (int k = 0; k < 128; k++) {
            float w2v = sW2[k * 64 + lane];
            float4 h03 = *(const float4*)&sh[k * HSTR + 0];
            float4 h47 = *(const float4*)&sh[k * HSTR + 4];
            acc[0] = fmaf(h03.x, w2v, acc[0]);
            acc[1] = fmaf(h03.y, w2v, acc[1]);
            acc[2] = fmaf(h03.z, w2v, acc[2]);
            acc[3] = fmaf(h03.w, w2v, acc[3]);
            acc[4] = fmaf(h47.x, w2v, acc[4]);
            acc[5] = fmaf(h47.y, w2v, acc[5]);
            acc[6] = fmaf(h47.z, w2v, acc[6]);
            acc[7] = fmaf(h47.w, w2v, acc[7]);
        }
#pragma unroll
        for (int m = 0; m < 8; m++) {
            int nn = n0 + m;
            if (nn < N) y2[(size_t)nn * 64 + lane] = acc[m];
        }
    }
}

// ---- layer 2 aggregate + bias/relu + W3 dot + layer-3 self-loop, wave/node
__global__ __launch_bounds__(256) void k_agg2_fused(
        const float* __restrict__ y2, const float* __restrict__ dis,
        const int* __restrict__ cursor, const int2* __restrict__ payload, int cap,
        const float* __restrict__ b2, const float* __restrict__ W3,
        const float* __restrict__ b3, float* __restrict__ s_out,
        float* __restrict__ out) {
    int t = threadIdx.x, wave = t >> 6, lane = t & 63;
    int n = blockIdx.x * 4 + wave;
    if (n >= N) return;
    float di = dis[n];
    float acc = di * di * y2[(size_t)n * 64 + lane];  // self-loop term
    int c = cursor[n];
    const int2* row = payload + (size_t)n * cap;
    int e = 0;
    for (; e + 1 < c; e += 2) {
        int2 p0 = row[e], p1 = row[e + 1];
        float n0 = dis[p0.x] * __int_as_float(p0.y) * di;
        float n1 = dis[p1.x] * __int_as_float(p1.y) * di;
        float v0 = y2[(size_t)p0.x * 64 + lane];
        float v1 = y2[(size_t)p1.x * 64 + lane];
        acc = fmaf(n0, v0, acc);
        acc = fmaf(n1, v1, acc);
    }
    if (e < c) {
        int2 p = row[e];
        acc = fmaf(dis[p.x] * __int_as_float(p.y) * di,
                   y2[(size_t)p.x * 64 + lane], acc);
    }
    float h = fmaxf(acc + b2[lane], 0.f);
    float p = h * W3[lane];
#pragma unroll
    for (int off = 32; off > 0; off >>= 1) p += __shfl_down(p, off);
    if (lane == 0) {
        s_out[n] = p;
        out[n] = di * di * p + b3[0];  // layer-3 self-loop + bias
    }
}

// ---- layer 3 aggregation: out[n] += sum nrm * s[src], thread per node ----
__global__ void k_agg3(const float* __restrict__ s, const float* __restrict__ dis,
                       const int* __restrict__ cursor, const int2* __restrict__ payload,
                       int cap, float* __restrict__ out) {
    int n = blockIdx.x * blockDim.x + threadIdx.x;
    if (n >= N) return;
    float di = dis[n], acc = 0.f;
    int c = cursor[n];
    const int2* row = payload + (size_t)n * cap;
    for (int e = 0; e < c; e++) {
        int2 p = row[e];
        acc = fmaf(dis[p.x] * __int_as_float(p.y) * di, s[p.x], acc);
    }
    out[n] += acc;
}

extern "C" void kernel_launch(void* const* d_in, const int* in_sizes, int n_in,
                              void* d_out, int out_size, void* d_ws, size_t ws_size,
                              hipStream_t stream) {
    const float* x  = (const float*)d_in[0];
    const int*   ei = (const int*)d_in[1];   // int32 (JAX x64-disabled)
    const int* src = ei;
    const int* dst = ei + E;
    const float* w  = (const float*)d_in[2];
    const float* W1 = (const float*)d_in[3];
    const float* b1 = (const float*)d_in[4];
    const float* W2 = (const float*)d_in[5];
    const float* b2 = (const float*)d_in[6];
    const float* W3 = (const float*)d_in[7];
    const float* b3 = (const float*)d_in[8];
    float* out = (float*)d_out;

    // fixed layout: cursor[N] | dis[N] | agg1[4N] | y2[64N]   (s aliases agg1)
    int*   cursor = (int*)d_ws;
    float* dis    = (float*)(cursor + N);
    float* agg1   = dis + N;
    float* y2     = agg1 + 4 * N;
    float* s      = agg1;                       // agg1 dead after k_fused_l1
    int2*  payload = (int2*)(y2 + (size_t)64 * N);
    size_t fixed_bytes = (size_t)(2 * N + 4 * N + 64 * N) * 4;
    int cap = (int)((ws_size - fixed_bytes) / ((size_t)N * 8));
    if (cap > 64) cap = 64;   // Poisson(8) max in-degree over 100k nodes << 35

    k_zero       <<<cdiv(N, 256), 256, 0, stream>>>(cursor);
    k_fill_direct<<<cdiv(E, 256), 256, 0, stream>>>(src, dst, w, cursor, payload, cap);
    k_deg_dis    <<<cdiv(N, 256), 256, 0, stream>>>(cursor, payload, cap, dis);
    k_agg1       <<<cdiv(N, 256), 256, 0, stream>>>((const float4*)x, dis, cursor, payload,
                                                    cap, (float4*)agg1);
    k_fused_l1   <<<cdiv(N, 64),  256, 0, stream>>>((const float4*)agg1, W1, b1, W2, y2);
    k_agg2_fused <<<cdiv(N, 4),   256, 0, stream>>>(y2, dis, cursor, payload, cap,
                                                    b2, W3, b3, s, out);
    k_agg3       <<<cdiv(N, 256), 256, 0, stream>>>(s, dis, cursor, payload, cap, out);
}

// Round 5
// 250.671 us; speedup vs baseline: 2.4949x; 1.0601x over previous
//
#include <hip/hip_runtime.h>
#include <hip/hip_fp16.h>

// GCN 3-layer, N=100000 nodes, E=800000 edges, f32.
// out = A_hat @ (relu(A_hat @ (relu((A_hat @ x) @ W1 + b1)) @ W2 + b2) @ W3) + b3
// A_hat = D^-1/2 (A + I) D^-1/2, weighted, deg over dst.
//
// R1: CSR + gather (no big atomic scatters). R2: k_fused_l1 register-blocked.
// R3: direct fixed-capacity bucketing (1 atomic + 8B store per edge).
// R4: y2 stored fp16 — layer-2 gather is fabric-BW bound on random 64-float
//     rows (R4 counters: 108.9 MB FETCH vs 25.6 MB array); halving bytes/row
//     halves the dominant traffic. |y2|~O(0.5), fp16 err -> ~1e-3 final.

constexpr int N = 100000;
constexpr int E = 800000;

static inline int cdiv(int a, int b) { return (a + b - 1) / b; }

__global__ void k_zero(int* __restrict__ cursor) {
    int i = blockIdx.x * blockDim.x + threadIdx.x;
    if (i < N) cursor[i] = 0;
}

// bucket edges by dst: payload[d*cap + pos] = {src, bits(w)}
__global__ void k_fill_direct(const int* __restrict__ src, const int* __restrict__ dst,
                              const float* __restrict__ w, int* __restrict__ cursor,
                              int2* __restrict__ payload, int cap) {
    int i = blockIdx.x * blockDim.x + threadIdx.x;
    if (i < E) {
        int d = dst[i];
        int pos = atomicAdd(&cursor[d], 1);
        if (pos < cap)
            payload[(size_t)d * cap + pos] = make_int2(src[i], __float_as_int(w[i]));
    }
}

// dis[n] = rsqrt(1 + sum w over row n); clamp stored count to cap
__global__ void k_deg_dis(int* __restrict__ cursor, const int2* __restrict__ payload,
                          int cap, float* __restrict__ dis) {
    int n = blockIdx.x * blockDim.x + threadIdx.x;
    if (n >= N) return;
    int c = cursor[n]; if (c > cap) { c = cap; cursor[n] = c; }
    const int2* row = payload + (size_t)n * cap;
    float sum = 1.0f;  // self-loop weight
    for (int e = 0; e < c; e++) sum += __int_as_float(row[e].y);
    dis[n] = rsqrtf(sum);
}

// ---- layer 1: aggregate-first (4 floats/node), thread per node ----------
__global__ void k_agg1(const float4* __restrict__ x, const float* __restrict__ dis,
                       const int* __restrict__ cursor, const int2* __restrict__ payload,
                       int cap, float4* __restrict__ agg1) {
    int n = blockIdx.x * blockDim.x + threadIdx.x;
    if (n >= N) return;
    float di = dis[n], sc = di * di;
    float4 v = x[n];
    float ax = sc * v.x, ay = sc * v.y, az = sc * v.z, aw = sc * v.w;
    int c = cursor[n];
    const int2* row = payload + (size_t)n * cap;
    for (int e = 0; e < c; e++) {
        int2 p = row[e];
        float nm = dis[p.x] * __int_as_float(p.y) * di;
        float4 u = x[p.x];
        ax = fmaf(nm, u.x, ax); ay = fmaf(nm, u.y, ay);
        az = fmaf(nm, u.z, az); aw = fmaf(nm, u.w, aw);
    }
    agg1[n] = make_float4(ax, ay, az, aw);
}

// ---- y2[n,:] = relu(agg1[n,:] @ W1 + b1) @ W2, stored fp16 --------------
constexpr int HSTR = 12;
__global__ __launch_bounds__(256) void k_fused_l1(const float4* __restrict__ agg1,
                                                  const float* __restrict__ W1,
                                                  const float* __restrict__ b1,
                                                  const float* __restrict__ W2,
                                                  __half* __restrict__ y2h) {
    __shared__ float sW2[128 * 64];            // 32 KB
    __shared__ float sh1[4][128 * HSTR];       // 4 waves x 6 KB
    int t = threadIdx.x;
    for (int i = t; i < 128 * 64; i += 256) sW2[i] = W2[i];
    int wave = t >> 6, lane = t & 63;
    float* sh = sh1[wave];
    __syncthreads();

#pragma unroll
    for (int g = 0; g < 2; g++) {
        int n0 = blockIdx.x * 64 + wave * 16 + g * 8;
#pragma unroll
        for (int r = 0; r < 2; r++) {
            int k = r * 64 + lane;
            float w0 = W1[0 * 128 + k], w1 = W1[1 * 128 + k];
            float w2 = W1[2 * 128 + k], w3 = W1[3 * 128 + k];
            float bb = b1[k];
            float hv[8];
#pragma unroll
            for (int m = 0; m < 8; m++) {
                int nn = n0 + m; if (nn >= N) nn = N - 1;
                float4 a = agg1[nn];
                float v = bb;
                v = fmaf(a.x, w0, v); v = fmaf(a.y, w1, v);
                v = fmaf(a.z, w2, v); v = fmaf(a.w, w3, v);
                hv[m] = fmaxf(v, 0.f);
            }
            *(float4*)&sh[k * HSTR + 0] = make_float4(hv[0], hv[1], hv[2], hv[3]);
            *(float4*)&sh[k * HSTR + 4] = make_float4(hv[4], hv[5], hv[6], hv[7]);
        }
        float acc[8] = {0.f, 0.f, 0.f, 0.f, 0.f, 0.f, 0.f, 0.f};
        for (int k = 0; k < 128; k++) {
            float w2v = sW2[k * 64 + lane];
            float4 h03 = *(const float4*)&sh[k * HSTR + 0];
            float4 h47 = *(const float4*)&sh[k * HSTR + 4];
            acc[0] = fmaf(h03.x, w2v, acc[0]);
            acc[1] = fmaf(h03.y, w2v, acc[1]);
            acc[2] = fmaf(h03.z, w2v, acc[2]);
            acc[3] = fmaf(h03.w, w2v, acc[3]);
            acc[4] = fmaf(h47.x, w2v, acc[4]);
            acc[5] = fmaf(h47.y, w2v, acc[5]);
            acc[6] = fmaf(h47.z, w2v, acc[6]);
            acc[7] = fmaf(h47.w, w2v, acc[7]);
        }
#pragma unroll
        for (int m = 0; m < 8; m++) {
            int nn = n0 + m;
            if (nn < N) y2h[(size_t)nn * 64 + lane] = __float2half(acc[m]);
        }
    }
}

// ---- layer 2 aggregate + bias/relu + W3 dot + layer-3 self-loop, wave/node
__global__ __launch_bounds__(256) void k_agg2_fused(
        const __half* __restrict__ y2h, const float* __restrict__ dis,
        const int* __restrict__ cursor, const int2* __restrict__ payload, int cap,
        const float* __restrict__ b2, const float* __restrict__ W3,
        const float* __restrict__ b3, float* __restrict__ s_out,
        float* __restrict__ out) {
    int t = threadIdx.x, wave = t >> 6, lane = t & 63;
    int n = blockIdx.x * 4 + wave;
    if (n >= N) return;
    float di = dis[n];
    float acc = di * di * __half2float(y2h[(size_t)n * 64 + lane]);  // self-loop
    int c = cursor[n];
    const int2* row = payload + (size_t)n * cap;
    int e = 0;
    for (; e + 3 < c; e += 4) {  // 4-way unroll: more outstanding 128B gathers
        int2 p0 = row[e], p1 = row[e + 1], p2 = row[e + 2], p3 = row[e + 3];
        float v0 = __half2float(y2h[(size_t)p0.x * 64 + lane]);
        float v1 = __half2float(y2h[(size_t)p1.x * 64 + lane]);
        float v2 = __half2float(y2h[(size_t)p2.x * 64 + lane]);
        float v3 = __half2float(y2h[(size_t)p3.x * 64 + lane]);
        acc = fmaf(dis[p0.x] * __int_as_float(p0.y) * di, v0, acc);
        acc = fmaf(dis[p1.x] * __int_as_float(p1.y) * di, v1, acc);
        acc = fmaf(dis[p2.x] * __int_as_float(p2.y) * di, v2, acc);
        acc = fmaf(dis[p3.x] * __int_as_float(p3.y) * di, v3, acc);
    }
    for (; e < c; e++) {
        int2 p = row[e];
        acc = fmaf(dis[p.x] * __int_as_float(p.y) * di,
                   __half2float(y2h[(size_t)p.x * 64 + lane]), acc);
    }
    float h = fmaxf(acc + b2[lane], 0.f);
    float p = h * W3[lane];
#pragma unroll
    for (int off = 32; off > 0; off >>= 1) p += __shfl_down(p, off);
    if (lane == 0) {
        s_out[n] = p;
        out[n] = di * di * p + b3[0];  // layer-3 self-loop + bias
    }
}

// ---- layer 3 aggregation: out[n] += sum nrm * s[src], thread per node ----
__global__ void k_agg3(const float* __restrict__ s, const float* __restrict__ dis,
                       const int* __restrict__ cursor, const int2* __restrict__ payload,
                       int cap, float* __restrict__ out) {
    int n = blockIdx.x * blockDim.x + threadIdx.x;
    if (n >= N) return;
    float di = dis[n], acc = 0.f;
    int c = cursor[n];
    const int2* row = payload + (size_t)n * cap;
    for (int e = 0; e < c; e++) {
        int2 p = row[e];
        acc = fmaf(dis[p.x] * __int_as_float(p.y) * di, s[p.x], acc);
    }
    out[n] += acc;
}

extern "C" void kernel_launch(void* const* d_in, const int* in_sizes, int n_in,
                              void* d_out, int out_size, void* d_ws, size_t ws_size,
                              hipStream_t stream) {
    const float* x  = (const float*)d_in[0];
    const int*   ei = (const int*)d_in[1];   // int32 (JAX x64-disabled)
    const int* src = ei;
    const int* dst = ei + E;
    const float* w  = (const float*)d_in[2];
    const float* W1 = (const float*)d_in[3];
    const float* b1 = (const float*)d_in[4];
    const float* W2 = (const float*)d_in[5];
    const float* b2 = (const float*)d_in[6];
    const float* W3 = (const float*)d_in[7];
    const float* b3 = (const float*)d_in[8];
    float* out = (float*)d_out;

    // layout: cursor[N] | dis[N] | agg1[4N] | y2h[64N fp16] | payload[N*cap]
    int*    cursor  = (int*)d_ws;
    float*  dis     = (float*)(cursor + N);
    float*  agg1    = dis + N;
    __half* y2h     = (__half*)(agg1 + 4 * N);
    float*  s       = agg1;                     // agg1 dead after k_fused_l1
    int2*   payload = (int2*)((char*)y2h + (size_t)64 * N * sizeof(__half));
    size_t fixed_bytes = (size_t)(2 * N + 4 * N) * 4 + (size_t)64 * N * 2;
    int cap = (int)((ws_size - fixed_bytes) / ((size_t)N * 8));
    if (cap > 64) cap = 64;   // Poisson(8) max in-degree over 100k nodes << 35

    k_zero       <<<cdiv(N, 256), 256, 0, stream>>>(cursor);
    k_fill_direct<<<cdiv(E, 256), 256, 0, stream>>>(src, dst, w, cursor, payload, cap);
    k_deg_dis    <<<cdiv(N, 256), 256, 0, stream>>>(cursor, payload, cap, dis);
    k_agg1       <<<cdiv(N, 256), 256, 0, stream>>>((const float4*)x, dis, cursor, payload,
                                                    cap, (float4*)agg1);
    k_fused_l1   <<<cdiv(N, 64),  256, 0, stream>>>((const float4*)agg1, W1, b1, W2, y2h);
    k_agg2_fused <<<cdiv(N, 4),   256, 0, stream>>>(y2h, dis, cursor, payload, cap,
                                                    b2, W3, b3, s, out);
    k_agg3       <<<cdiv(N, 256), 256, 0, stream>>>(s, dis, cursor, payload, cap, out);
}

// Round 6
// 216.782 us; speedup vs baseline: 2.8850x; 1.1563x over previous
//
#include <hip/hip_runtime.h>
#include <hip/hip_fp16.h>

// GCN 3-layer, N=100000 nodes, E=800000 edges, f32.
// out = A_hat @ (relu(A_hat @ (relu((A_hat @ x) @ W1 + b1)) @ W2 + b2) @ W3) + b3
// A_hat = D^-1/2 (A + I) D^-1/2, weighted, deg over dst.
//
// R1: CSR + gather. R3: direct fixed-capacity bucketing (1 atomic/edge).
// R4: y2 fp16 (layer-2 gather fabric-BW bound). R5 counters: k_fused_l1 was
//     LDS-issue bound (512 ds_read_b128/group, 56KB LDS -> 2 blk/CU, occ 16%).
// R6: k_fused_l1 on MFMA (v_mfma_f32_16x16x32_f16): h1 via VALU into per-wave
//     LDS tile, W2 as 16 register B-fragments, 16 MFMA per 16 nodes.
//     LDS 56KB->17.4KB, ~36 LDS instrs/group instead of 768.

constexpr int N = 100000;
constexpr int E = 800000;

static inline int cdiv(int a, int b) { return (a + b - 1) / b; }

typedef __attribute__((ext_vector_type(8))) _Float16 f16x8;
typedef __attribute__((ext_vector_type(4))) float f32x4;

__global__ void k_zero(int* __restrict__ cursor) {
    int i = blockIdx.x * blockDim.x + threadIdx.x;
    if (i < N) cursor[i] = 0;
}

// bucket edges by dst: payload[d*cap + pos] = {src, bits(w)}
__global__ void k_fill_direct(const int* __restrict__ src, const int* __restrict__ dst,
                              const float* __restrict__ w, int* __restrict__ cursor,
                              int2* __restrict__ payload, int cap) {
    int i = blockIdx.x * blockDim.x + threadIdx.x;
    if (i < E) {
        int d = dst[i];
        int pos = atomicAdd(&cursor[d], 1);
        if (pos < cap)
            payload[(size_t)d * cap + pos] = make_int2(src[i], __float_as_int(w[i]));
    }
}

// dis[n] = rsqrt(1 + sum w over row n); clamp stored count to cap
__global__ void k_deg_dis(int* __restrict__ cursor, const int2* __restrict__ payload,
                          int cap, float* __restrict__ dis) {
    int n = blockIdx.x * blockDim.x + threadIdx.x;
    if (n >= N) return;
    int c = cursor[n]; if (c > cap) { c = cap; cursor[n] = c; }
    const int2* row = payload + (size_t)n * cap;
    float sum = 1.0f;  // self-loop weight
    for (int e = 0; e < c; e++) sum += __int_as_float(row[e].y);
    dis[n] = rsqrtf(sum);
}

// ---- layer 1: aggregate-first (4 floats/node), thread per node ----------
__global__ void k_agg1(const float4* __restrict__ x, const float* __restrict__ dis,
                       const int* __restrict__ cursor, const int2* __restrict__ payload,
                       int cap, float4* __restrict__ agg1) {
    int n = blockIdx.x * blockDim.x + threadIdx.x;
    if (n >= N) return;
    float di = dis[n], sc = di * di;
    float4 v = x[n];
    float ax = sc * v.x, ay = sc * v.y, az = sc * v.z, aw = sc * v.w;
    int c = cursor[n];
    const int2* row = payload + (size_t)n * cap;
    for (int e = 0; e < c; e++) {
        int2 p = row[e];
        float nm = dis[p.x] * __int_as_float(p.y) * di;
        float4 u = x[p.x];
        ax = fmaf(nm, u.x, ax); ay = fmaf(nm, u.y, ay);
        az = fmaf(nm, u.z, az); aw = fmaf(nm, u.w, aw);
    }
    agg1[n] = make_float4(ax, ay, az, aw);
}

// ---- y2[n,:] = relu(agg1[n,:] @ W1 + b1) @ W2, fp16 out, via MFMA -------
// Per wave: 2 groups of 16 nodes. Phase A: lane-per-k h1 -> LDS tile,
// row stride 136 f16 (272 B: 16B-aligned b128, uniform 8-lanes/bank).
// Phase B: A-frag = h1[m=lane&15][k=(lane>>4)*8+j]; B-frags (W2, f16) held in
// regs: B[k=(lane>>4)*8+j][n=lane&15]; C: row(m)=(lane>>4)*4+reg, col(n)=lane&15.
constexpr int HROW = 136;  // f16 units per node row in LDS
__global__ __launch_bounds__(256) void k_fused_l1(const float4* __restrict__ agg1,
                                                  const float* __restrict__ W1,
                                                  const float* __restrict__ b1,
                                                  const float* __restrict__ W2,
                                                  __half* __restrict__ y2h) {
    __shared__ _Float16 h1lds[4][16 * HROW];   // 4 waves x 4352 B = 17408 B
    int t = threadIdx.x, wave = t >> 6, lane = t & 63;
    int q = lane >> 4, c = lane & 15;
    _Float16* sh = h1lds[wave];

    // W1 columns for this lane's two k values (once per kernel)
    int k1 = lane, k2 = lane + 64;
    float w10 = W1[0 * 128 + k1], w11 = W1[1 * 128 + k1];
    float w12 = W1[2 * 128 + k1], w13 = W1[3 * 128 + k1], bb1 = b1[k1];
    float w20 = W1[0 * 128 + k2], w21 = W1[1 * 128 + k2];
    float w22 = W1[2 * 128 + k2], w23 = W1[3 * 128 + k2], bb2 = b1[k2];

    // B-fragments: Bf[kt][nt] lane holds W2[kt*32 + q*8 + j][nt*16 + c], j=0..7
    f16x8 Bf[4][4];
#pragma unroll
    for (int kt = 0; kt < 4; kt++)
#pragma unroll
        for (int nt = 0; nt < 4; nt++)
#pragma unroll
            for (int j = 0; j < 8; j++)
                Bf[kt][nt][j] = (_Float16)W2[(kt * 32 + q * 8 + j) * 64 + nt * 16 + c];

    int wave_id = blockIdx.x * 4 + wave;
#pragma unroll
    for (int g = 0; g < 2; g++) {
        int n0 = (wave_id * 2 + g) * 16;
        if (n0 >= N) break;            // N = 6250*16: groups are always full
        // Phase A: h1[m][k] = relu(b1[k] + agg1[n0+m] . W1[:,k]) for k1,k2
#pragma unroll
        for (int m = 0; m < 16; m++) {
            float4 a = agg1[n0 + m];   // wave-uniform broadcast load
            float v1 = bb1, v2 = bb2;
            v1 = fmaf(a.x, w10, v1); v1 = fmaf(a.y, w11, v1);
            v1 = fmaf(a.z, w12, v1); v1 = fmaf(a.w, w13, v1);
            v2 = fmaf(a.x, w20, v2); v2 = fmaf(a.y, w21, v2);
            v2 = fmaf(a.z, w22, v2); v2 = fmaf(a.w, w23, v2);
            sh[m * HROW + k1] = (_Float16)fmaxf(v1, 0.f);
            sh[m * HROW + k2] = (_Float16)fmaxf(v2, 0.f);
        }
        // Phase B: 4 K-tiles x 4 N-tiles of 16x16x32 MFMA (wave-local, no barrier)
        f32x4 C[4] = {{0.f, 0.f, 0.f, 0.f}, {0.f, 0.f, 0.f, 0.f},
                      {0.f, 0.f, 0.f, 0.f}, {0.f, 0.f, 0.f, 0.f}};
#pragma unroll
        for (int kt = 0; kt < 4; kt++) {
            f16x8 A = *(const f16x8*)&sh[c * HROW + kt * 32 + q * 8];
#pragma unroll
            for (int nt = 0; nt < 4; nt++)
                C[nt] = __builtin_amdgcn_mfma_f32_16x16x32_f16(A, Bf[kt][nt], C[nt], 0, 0, 0);
        }
#pragma unroll
        for (int nt = 0; nt < 4; nt++)
#pragma unroll
            for (int r = 0; r < 4; r++) {
                int node = n0 + q * 4 + r;                    // row = q*4 + reg
                y2h[(size_t)node * 64 + nt * 16 + c] = __float2half(C[nt][r]);
            }
    }
}

// ---- layer 2 aggregate + bias/relu + W3 dot + layer-3 self-loop, wave/node
__global__ __launch_bounds__(256) void k_agg2_fused(
        const __half* __restrict__ y2h, const float* __restrict__ dis,
        const int* __restrict__ cursor, const int2* __restrict__ payload, int cap,
        const float* __restrict__ b2, const float* __restrict__ W3,
        const float* __restrict__ b3, float* __restrict__ s_out,
        float* __restrict__ out) {
    int t = threadIdx.x, wave = t >> 6, lane = t & 63;
    int n = blockIdx.x * 4 + wave;
    if (n >= N) return;
    float di = dis[n];
    float acc = di * di * __half2float(y2h[(size_t)n * 64 + lane]);  // self-loop
    int c = cursor[n];
    const int2* row = payload + (size_t)n * cap;
    int e = 0;
    for (; e + 3 < c; e += 4) {  // 4-way unroll: more outstanding 128B gathers
        int2 p0 = row[e], p1 = row[e + 1], p2 = row[e + 2], p3 = row[e + 3];
        float v0 = __half2float(y2h[(size_t)p0.x * 64 + lane]);
        float v1 = __half2float(y2h[(size_t)p1.x * 64 + lane]);
        float v2 = __half2float(y2h[(size_t)p2.x * 64 + lane]);
        float v3 = __half2float(y2h[(size_t)p3.x * 64 + lane]);
        acc = fmaf(dis[p0.x] * __int_as_float(p0.y) * di, v0, acc);
        acc = fmaf(dis[p1.x] * __int_as_float(p1.y) * di, v1, acc);
        acc = fmaf(dis[p2.x] * __int_as_float(p2.y) * di, v2, acc);
        acc = fmaf(dis[p3.x] * __int_as_float(p3.y) * di, v3, acc);
    }
    for (; e < c; e++) {
        int2 p = row[e];
        acc = fmaf(dis[p.x] * __int_as_float(p.y) * di,
                   __half2float(y2h[(size_t)p.x * 64 + lane]), acc);
    }
    float h = fmaxf(acc + b2[lane], 0.f);
    float p = h * W3[lane];
#pragma unroll
    for (int off = 32; off > 0; off >>= 1) p += __shfl_down(p, off);
    if (lane == 0) {
        s_out[n] = p;
        out[n] = di * di * p + b3[0];  // layer-3 self-loop + bias
    }
}

// ---- layer 3 aggregation: out[n] += sum nrm * s[src], thread per node ----
__global__ void k_agg3(const float* __restrict__ s, const float* __restrict__ dis,
                       const int* __restrict__ cursor, const int2* __restrict__ payload,
                       int cap, float* __restrict__ out) {
    int n = blockIdx.x * blockDim.x + threadIdx.x;
    if (n >= N) return;
    float di = dis[n], acc = 0.f;
    int c = cursor[n];
    const int2* row = payload + (size_t)n * cap;
    for (int e = 0; e < c; e++) {
        int2 p = row[e];
        acc = fmaf(dis[p.x] * __int_as_float(p.y) * di, s[p.x], acc);
    }
    out[n] += acc;
}

extern "C" void kernel_launch(void* const* d_in, const int* in_sizes, int n_in,
                              void* d_out, int out_size, void* d_ws, size_t ws_size,
                              hipStream_t stream) {
    const float* x  = (const float*)d_in[0];
    const int*   ei = (const int*)d_in[1];   // int32 (JAX x64-disabled)
    const int* src = ei;
    const int* dst = ei + E;
    const float* w  = (const float*)d_in[2];
    const float* W1 = (const float*)d_in[3];
    const float* b1 = (const float*)d_in[4];
    const float* W2 = (const float*)d_in[5];
    const float* b2 = (const float*)d_in[6];
    const float* W3 = (const float*)d_in[7];
    const float* b3 = (const float*)d_in[8];
    float* out = (float*)d_out;

    // layout: cursor[N] | dis[N] | agg1[4N] | y2h[64N fp16] | payload[N*cap]
    int*    cursor  = (int*)d_ws;
    float*  dis     = (float*)(cursor + N);
    float*  agg1    = dis + N;
    __half* y2h     = (__half*)(agg1 + 4 * N);
    float*  s       = agg1;                     // agg1 dead after k_fused_l1
    int2*   payload = (int2*)((char*)y2h + (size_t)64 * N * sizeof(__half));
    size_t fixed_bytes = (size_t)(2 * N + 4 * N) * 4 + (size_t)64 * N * 2;
    int cap = (int)((ws_size - fixed_bytes) / ((size_t)N * 8));
    if (cap > 64) cap = 64;   // Poisson(8) max in-degree over 100k nodes << 35

    k_zero       <<<cdiv(N, 256), 256, 0, stream>>>(cursor);
    k_fill_direct<<<cdiv(E, 256), 256, 0, stream>>>(src, dst, w, cursor, payload, cap);
    k_deg_dis    <<<cdiv(N, 256), 256, 0, stream>>>(cursor, payload, cap, dis);
    k_agg1       <<<cdiv(N, 256), 256, 0, stream>>>((const float4*)x, dis, cursor, payload,
                                                    cap, (float4*)agg1);
    k_fused_l1   <<<cdiv(N / 16, 8), 256, 0, stream>>>((const float4*)agg1, W1, b1, W2, y2h);
    k_agg2_fused <<<cdiv(N, 4),   256, 0, stream>>>(y2h, dis, cursor, payload, cap,
                                                    b2, W3, b3, s, out);
    k_agg3       <<<cdiv(N, 256), 256, 0, stream>>>(s, dis, cursor, payload, cap, out);
}

// Round 7
// 198.590 us; speedup vs baseline: 3.1493x; 1.0916x over previous
//
#include <hip/hip_runtime.h>
#include <hip/hip_fp16.h>

// GCN 3-layer, N=100000 nodes, E=800000 edges, f32.
// out = A_hat @ (relu(A_hat @ (relu((A_hat @ x) @ W1 + b1)) @ W2 + b2) @ W3) + b3
// A_hat = D^-1/2 (A + I) D^-1/2, weighted, deg over dst.
//
// R3: direct bucketing (1 global atomic/edge). R4: y2 fp16. R6: fused_l1 on MFMA.
// R7: R6 counters showed k_fill_direct at 53us = 800k atomic write-throughs
//     (WRITE 49.6MB at ~1TB/s random). Replaced by 2-phase counting bucket sort:
//     k_coarse: LDS histogram by dst>>8 (391 buckets), ~49k global atomics to
//               reserve ranges, 8B records into bucket-local windows.
//     k_fine:   per-bucket block, LDS atomics for exact per-node slots, payload
//               writes confined to 131KB window; computes cursor/dis (deg_dis gone).

constexpr int N = 100000;
constexpr int E = 800000;
constexpr int NBKT = 391;    // buckets of 256 nodes: (100000+255)>>8
constexpr int BCAP = 3072;   // per-bucket capacity; mean 2046, sd ~45 -> 22 sigma
constexpr int GC = 125;      // coarse blocks; 125 * 6400 = E exactly
constexpr int CHUNK = 6400;  // 25 full 256-thread iterations

static inline int cdiv(int a, int b) { return (a + b - 1) / b; }

typedef __attribute__((ext_vector_type(8))) _Float16 f16x8;
typedef __attribute__((ext_vector_type(4))) float f32x4;

__global__ void k_zero(int* __restrict__ bucket_cursor) {
    int i = blockIdx.x * blockDim.x + threadIdx.x;
    if (i < NBKT) bucket_cursor[i] = 0;
}

// coarse bucketing by dst>>8: record = {src | (dst&255)<<17, bits(w)}
__global__ __launch_bounds__(256) void k_coarse(const int* __restrict__ src,
                                                const int* __restrict__ dst,
                                                const float* __restrict__ w,
                                                int* __restrict__ bucket_cursor,
                                                int2* __restrict__ sorted) {
    __shared__ int hist[NBKT];
    __shared__ int base[NBKT];
    int t = threadIdx.x;
    for (int i = t; i < NBKT; i += 256) hist[i] = 0;
    __syncthreads();
    int begin = blockIdx.x * CHUNK;
    int ranks[25];
#pragma unroll
    for (int i = 0; i < 25; i++) {
        int e = begin + i * 256 + t;
        ranks[i] = atomicAdd(&hist[dst[e] >> 8], 1);   // LDS atomic: local rank
    }
    __syncthreads();
    for (int i = t; i < NBKT; i += 256) {
        int h = hist[i];
        base[i] = h ? atomicAdd(&bucket_cursor[i], h) : 0;  // ~389 global atomics/block
    }
    __syncthreads();
#pragma unroll
    for (int i = 0; i < 25; i++) {
        int e = begin + i * 256 + t;
        int d = dst[e], b = d >> 8;
        int pos = base[b] + ranks[i];
        if (pos < BCAP)
            sorted[(size_t)b * BCAP + pos] =
                make_int2(src[e] | ((d & 255) << 17), __float_as_int(w[e]));
    }
}

// fine bucketing: one block per coarse bucket (256 nodes). LDS per-node slot
// counters + w-sums; payload writes land in this bucket's 131KB window.
// Also emits cursor[n] and dis[n] (replaces k_deg_dis).
__global__ __launch_bounds__(256) void k_fine(const int2* __restrict__ sorted,
                                              const int* __restrict__ bucket_cursor,
                                              int cap, int2* __restrict__ payload,
                                              int* __restrict__ cursor,
                                              float* __restrict__ dis) {
    __shared__ int   ncnt[256];
    __shared__ float nwsum[256];
    int t = threadIdx.x, b = blockIdx.x;
    ncnt[t] = 0;
    nwsum[t] = 1.0f;  // self-loop weight pre-seeded
    __syncthreads();
    int cnt = bucket_cursor[b]; if (cnt > BCAP) cnt = BCAP;
    const int2* seg = sorted + (size_t)b * BCAP;
    for (int i = t; i < cnt; i += 256) {
        int2 r = seg[i];
        int s = r.x & 0x1FFFF, dlo = r.x >> 17;
        int pos = atomicAdd(&ncnt[dlo], 1);
        atomicAdd(&nwsum[dlo], __int_as_float(r.y));
        if (pos < cap)
            payload[(size_t)(b * 256 + dlo) * cap + pos] = make_int2(s, r.y);
    }
    __syncthreads();
    int n = b * 256 + t;
    if (n < N) {
        int c = ncnt[t]; if (c > cap) c = cap;
        cursor[n] = c;
        dis[n] = rsqrtf(nwsum[t]);
    }
}

// ---- layer 1: aggregate-first (4 floats/node), thread per node ----------
__global__ void k_agg1(const float4* __restrict__ x, const float* __restrict__ dis,
                       const int* __restrict__ cursor, const int2* __restrict__ payload,
                       int cap, float4* __restrict__ agg1) {
    int n = blockIdx.x * blockDim.x + threadIdx.x;
    if (n >= N) return;
    float di = dis[n], sc = di * di;
    float4 v = x[n];
    float ax = sc * v.x, ay = sc * v.y, az = sc * v.z, aw = sc * v.w;
    int c = cursor[n];
    const int2* row = payload + (size_t)n * cap;
    for (int e = 0; e < c; e++) {
        int2 p = row[e];
        float nm = dis[p.x] * __int_as_float(p.y) * di;
        float4 u = x[p.x];
        ax = fmaf(nm, u.x, ax); ay = fmaf(nm, u.y, ay);
        az = fmaf(nm, u.z, az); aw = fmaf(nm, u.w, aw);
    }
    agg1[n] = make_float4(ax, ay, az, aw);
}

// ---- y2[n,:] = relu(agg1[n,:] @ W1 + b1) @ W2, fp16 out, via MFMA -------
constexpr int HROW = 136;  // f16 units per node row in LDS
__global__ __launch_bounds__(256) void k_fused_l1(const float4* __restrict__ agg1,
                                                  const float* __restrict__ W1,
                                                  const float* __restrict__ b1,
                                                  const float* __restrict__ W2,
                                                  __half* __restrict__ y2h) {
    __shared__ _Float16 h1lds[4][16 * HROW];   // 4 waves x 4352 B = 17408 B
    int t = threadIdx.x, wave = t >> 6, lane = t & 63;
    int q = lane >> 4, c = lane & 15;
    _Float16* sh = h1lds[wave];

    int k1 = lane, k2 = lane + 64;
    float w10 = W1[0 * 128 + k1], w11 = W1[1 * 128 + k1];
    float w12 = W1[2 * 128 + k1], w13 = W1[3 * 128 + k1], bb1 = b1[k1];
    float w20 = W1[0 * 128 + k2], w21 = W1[1 * 128 + k2];
    float w22 = W1[2 * 128 + k2], w23 = W1[3 * 128 + k2], bb2 = b1[k2];

    // B-fragments: Bf[kt][nt] lane holds W2[kt*32 + q*8 + j][nt*16 + c], j=0..7
    f16x8 Bf[4][4];
#pragma unroll
    for (int kt = 0; kt < 4; kt++)
#pragma unroll
        for (int nt = 0; nt < 4; nt++)
#pragma unroll
            for (int j = 0; j < 8; j++)
                Bf[kt][nt][j] = (_Float16)W2[(kt * 32 + q * 8 + j) * 64 + nt * 16 + c];

    int wave_id = blockIdx.x * 4 + wave;
#pragma unroll
    for (int g = 0; g < 2; g++) {
        int n0 = (wave_id * 2 + g) * 16;
        if (n0 >= N) break;
#pragma unroll
        for (int m = 0; m < 16; m++) {
            float4 a = agg1[n0 + m];   // wave-uniform broadcast load
            float v1 = bb1, v2 = bb2;
            v1 = fmaf(a.x, w10, v1); v1 = fmaf(a.y, w11, v1);
            v1 = fmaf(a.z, w12, v1); v1 = fmaf(a.w, w13, v1);
            v2 = fmaf(a.x, w20, v2); v2 = fmaf(a.y, w21, v2);
            v2 = fmaf(a.z, w22, v2); v2 = fmaf(a.w, w23, v2);
            sh[m * HROW + k1] = (_Float16)fmaxf(v1, 0.f);
            sh[m * HROW + k2] = (_Float16)fmaxf(v2, 0.f);
        }
        f32x4 C[4] = {{0.f, 0.f, 0.f, 0.f}, {0.f, 0.f, 0.f, 0.f},
                      {0.f, 0.f, 0.f, 0.f}, {0.f, 0.f, 0.f, 0.f}};
#pragma unroll
        for (int kt = 0; kt < 4; kt++) {
            f16x8 A = *(const f16x8*)&sh[c * HROW + kt * 32 + q * 8];
#pragma unroll
            for (int nt = 0; nt < 4; nt++)
                C[nt] = __builtin_amdgcn_mfma_f32_16x16x32_f16(A, Bf[kt][nt], C[nt], 0, 0, 0);
        }
#pragma unroll
        for (int nt = 0; nt < 4; nt++)
#pragma unroll
            for (int r = 0; r < 4; r++) {
                int node = n0 + q * 4 + r;                    // row = q*4 + reg
                y2h[(size_t)node * 64 + nt * 16 + c] = __float2half(C[nt][r]);
            }
    }
}

// ---- layer 2 aggregate + bias/relu + W3 dot + layer-3 self-loop, wave/node
__global__ __launch_bounds__(256) void k_agg2_fused(
        const __half* __restrict__ y2h, const float* __restrict__ dis,
        const int* __restrict__ cursor, const int2* __restrict__ payload, int cap,
        const float* __restrict__ b2, const float* __restrict__ W3,
        const float* __restrict__ b3, float* __restrict__ s_out,
        float* __restrict__ out) {
    int t = threadIdx.x, wave = t >> 6, lane = t & 63;
    int n = blockIdx.x * 4 + wave;
    if (n >= N) return;
    float di = dis[n];
    float acc = di * di * __half2float(y2h[(size_t)n * 64 + lane]);  // self-loop
    int c = cursor[n];
    const int2* row = payload + (size_t)n * cap;
    int e = 0;
    for (; e + 3 < c; e += 4) {
        int2 p0 = row[e], p1 = row[e + 1], p2 = row[e + 2], p3 = row[e + 3];
        float v0 = __half2float(y2h[(size_t)p0.x * 64 + lane]);
        float v1 = __half2float(y2h[(size_t)p1.x * 64 + lane]);
        float v2 = __half2float(y2h[(size_t)p2.x * 64 + lane]);
        float v3 = __half2float(y2h[(size_t)p3.x * 64 + lane]);
        acc = fmaf(dis[p0.x] * __int_as_float(p0.y) * di, v0, acc);
        acc = fmaf(dis[p1.x] * __int_as_float(p1.y) * di, v1, acc);
        acc = fmaf(dis[p2.x] * __int_as_float(p2.y) * di, v2, acc);
        acc = fmaf(dis[p3.x] * __int_as_float(p3.y) * di, v3, acc);
    }
    for (; e < c; e++) {
        int2 p = row[e];
        acc = fmaf(dis[p.x] * __int_as_float(p.y) * di,
                   __half2float(y2h[(size_t)p.x * 64 + lane]), acc);
    }
    float h = fmaxf(acc + b2[lane], 0.f);
    float p = h * W3[lane];
#pragma unroll
    for (int off = 32; off > 0; off >>= 1) p += __shfl_down(p, off);
    if (lane == 0) {
        s_out[n] = p;
        out[n] = di * di * p + b3[0];  // layer-3 self-loop + bias
    }
}

// ---- layer 3 aggregation: out[n] += sum nrm * s[src], thread per node ----
__global__ void k_agg3(const float* __restrict__ s, const float* __restrict__ dis,
                       const int* __restrict__ cursor, const int2* __restrict__ payload,
                       int cap, float* __restrict__ out) {
    int n = blockIdx.x * blockDim.x + threadIdx.x;
    if (n >= N) return;
    float di = dis[n], acc = 0.f;
    int c = cursor[n];
    const int2* row = payload + (size_t)n * cap;
    for (int e = 0; e < c; e++) {
        int2 p = row[e];
        acc = fmaf(dis[p.x] * __int_as_float(p.y) * di, s[p.x], acc);
    }
    out[n] += acc;
}

extern "C" void kernel_launch(void* const* d_in, const int* in_sizes, int n_in,
                              void* d_out, int out_size, void* d_ws, size_t ws_size,
                              hipStream_t stream) {
    const float* x  = (const float*)d_in[0];
    const int*   ei = (const int*)d_in[1];   // int32 (JAX x64-disabled)
    const int* src = ei;
    const int* dst = ei + E;
    const float* w  = (const float*)d_in[2];
    const float* W1 = (const float*)d_in[3];
    const float* b1 = (const float*)d_in[4];
    const float* W2 = (const float*)d_in[5];
    const float* b2 = (const float*)d_in[6];
    const float* W3 = (const float*)d_in[7];
    const float* b3 = (const float*)d_in[8];
    float* out = (float*)d_out;

    // layout: bcur[512] | cursor[N] | dis[N] | agg1[4N] | y2h[64N h] |
    //         sorted[NBKT*BCAP int2] | payload[N*cap int2]
    int*    bcur    = (int*)d_ws;
    int*    cursor  = bcur + 512;
    float*  dis     = (float*)(cursor + N);
    float*  agg1    = dis + N;
    __half* y2h     = (__half*)(agg1 + 4 * N);
    float*  s       = agg1;                     // agg1 dead after k_fused_l1
    int2*   sorted  = (int2*)((char*)y2h + (size_t)64 * N * sizeof(__half));
    int2*   payload = sorted + (size_t)NBKT * BCAP;
    size_t fixed_bytes = (size_t)(512 + 2 * N + 4 * N) * 4 + (size_t)64 * N * 2
                       + (size_t)NBKT * BCAP * 8;
    int cap = (int)((ws_size - fixed_bytes) / ((size_t)N * 8));
    if (cap > 64) cap = 64;   // Poisson(8) max in-degree over 100k nodes << 35

    k_zero       <<<cdiv(NBKT, 256), 256, 0, stream>>>(bcur);
    k_coarse     <<<GC,           256, 0, stream>>>(src, dst, w, bcur, sorted);
    k_fine       <<<NBKT,         256, 0, stream>>>(sorted, bcur, cap, payload, cursor, dis);
    k_agg1       <<<cdiv(N, 256), 256, 0, stream>>>((const float4*)x, dis, cursor, payload,
                                                    cap, (float4*)agg1);
    k_fused_l1   <<<cdiv(N / 16, 8), 256, 0, stream>>>((const float4*)agg1, W1, b1, W2, y2h);
    k_agg2_fused <<<cdiv(N, 4),   256, 0, stream>>>(y2h, dis, cursor, payload, cap,
                                                    b2, W3, b3, s, out);
    k_agg3       <<<cdiv(N, 256), 256, 0, stream>>>(s, dis, cursor, payload, cap, out);
}

// Round 8
// 169.864 us; speedup vs baseline: 3.6818x; 1.1691x over previous
//
#include <hip/hip_runtime.h>
#include <hip/hip_fp16.h>

// GCN 3-layer, N=100000 nodes, E=800000 edges, f32.
// out = A_hat @ (relu(A_hat @ (relu((A_hat @ x) @ W1 + b1)) @ W2 + b2) @ W3) + b3
// A_hat = D^-1/2 (A + I) D^-1/2, weighted, deg over dst.
//
// R6: fused_l1 on MFMA. R7: 2-phase counting bucket sort (k_coarse/k_fine).
// R8: R7 counters showed k_agg2 issue-bound (~26 cyc/edge: 3 VMEM + redundant
//     per-lane norm) and agg1/agg3 latency-bound at 6 waves/CU. Rewrite:
//     - k_fine seeds self-loop entry {n,1.0} + pads rows to x8 with {0,0.0}
//     - k_agg1 computes norm once/edge, writes back to payload.y
//     - k_agg2: 4 nodes x 2 slots x 8 feat-octets/wave; 2 VMEM per 8 edges
//     - k_agg3: 8 nodes x 8 slots/wave; writes out = acc + b3 directly

constexpr int N = 100000;
constexpr int E = 800000;
constexpr int NBKT = 391;    // buckets of 256 nodes
constexpr int BCAP = 3072;   // per-bucket capacity; mean 2046, ~22 sigma margin
constexpr int GC = 125;      // coarse blocks; 125 * 6400 = E exactly
constexpr int CHUNK = 6400;

static inline int cdiv(int a, int b) { return (a + b - 1) / b; }

typedef __attribute__((ext_vector_type(8))) _Float16 f16x8;
typedef __attribute__((ext_vector_type(4))) float f32x4;

__global__ void k_zero(int* __restrict__ bucket_cursor) {
    int i = blockIdx.x * blockDim.x + threadIdx.x;
    if (i < NBKT) bucket_cursor[i] = 0;
}

// coarse bucketing by dst>>8: record = {src | (dst&255)<<17, bits(w)}
__global__ __launch_bounds__(256) void k_coarse(const int* __restrict__ src,
                                                const int* __restrict__ dst,
                                                const float* __restrict__ w,
                                                int* __restrict__ bucket_cursor,
                                                int2* __restrict__ sorted) {
    __shared__ int hist[NBKT];
    __shared__ int base[NBKT];
    int t = threadIdx.x;
    for (int i = t; i < NBKT; i += 256) hist[i] = 0;
    __syncthreads();
    int begin = blockIdx.x * CHUNK;
    int ranks[25];
#pragma unroll
    for (int i = 0; i < 25; i++) {
        int e = begin + i * 256 + t;
        ranks[i] = atomicAdd(&hist[dst[e] >> 8], 1);
    }
    __syncthreads();
    for (int i = t; i < NBKT; i += 256) {
        int h = hist[i];
        base[i] = h ? atomicAdd(&bucket_cursor[i], h) : 0;
    }
    __syncthreads();
#pragma unroll
    for (int i = 0; i < 25; i++) {
        int e = begin + i * 256 + t;
        int d = dst[e], b = d >> 8;
        int pos = base[b] + ranks[i];
        if (pos < BCAP)
            sorted[(size_t)b * BCAP + pos] =
                make_int2(src[e] | ((d & 255) << 17), __float_as_int(w[e]));
    }
}

// fine bucketing: one block per bucket. Slot 0 of each row = self-loop {n,1.0};
// rows padded to multiple of 8 with {0, 0.0f} (norm-neutral). Emits cursor/dis.
__global__ __launch_bounds__(256) void k_fine(const int2* __restrict__ sorted,
                                              const int* __restrict__ bucket_cursor,
                                              int cap, int2* __restrict__ payload,
                                              int* __restrict__ cursor,
                                              float* __restrict__ dis) {
    __shared__ int   ncnt[256];
    __shared__ float nwsum[256];
    int t = threadIdx.x, b = blockIdx.x;
    ncnt[t] = 1;      // slot 0 reserved for self-loop
    nwsum[t] = 1.0f;  // self-loop weight
    __syncthreads();
    int cnt = bucket_cursor[b]; if (cnt > BCAP) cnt = BCAP;
    const int2* seg = sorted + (size_t)b * BCAP;
    for (int i = t; i < cnt; i += 256) {
        int2 r = seg[i];
        int s = r.x & 0x1FFFF, dlo = r.x >> 17;
        int pos = atomicAdd(&ncnt[dlo], 1);
        atomicAdd(&nwsum[dlo], __int_as_float(r.y));
        if (pos < cap)
            payload[(size_t)(b * 256 + dlo) * cap + pos] = make_int2(s, r.y);
    }
    __syncthreads();
    int n = b * 256 + t;
    if (n < N) {
        int c = ncnt[t]; if (c > cap) c = cap;
        int2* row = payload + (size_t)n * cap;
        row[0] = make_int2(n, __float_as_int(1.0f));   // self-loop entry
        int cpad = (c + 7) & ~7;
        for (int e = c; e < cpad; e++) row[e] = make_int2(0, 0);  // {src0, w=0}
        cursor[n] = c;
        dis[n] = rsqrtf(nwsum[t]);
    }
}

// ---- layer 1 aggregation: 4 nodes x 4 edge-slots x 4 feats per wave ------
// Computes norm once per edge and writes it back into payload.y for agg2/agg3.
__global__ __launch_bounds__(256) void k_agg1(const float* __restrict__ x,
                                              const float* __restrict__ dis,
                                              const int* __restrict__ cursor,
                                              int2* __restrict__ payload, int cap,
                                              float* __restrict__ agg1) {
    int t = threadIdx.x, lane = t & 63, wave = t >> 6;
    int nsub = lane >> 4, slot = (lane >> 2) & 3, feat = lane & 3;
    int n = (blockIdx.x * 4 + wave) * 4 + nsub;   // grid exact: 6250*16 = N
    float di = dis[n];
    int cnt = cursor[n];
    int2* row = payload + (size_t)n * cap;
    int iters = (cnt + 3) >> 2;
    float acc = 0.f;
    for (int it = 0; it < iters; it++) {
        int e = it * 4 + slot;
        int2 p = row[e];
        float nm = dis[p.x] * __int_as_float(p.y) * di;  // self: di*1*di = di^2
        float xv = x[p.x * 4 + feat];
        acc = fmaf(nm, xv, acc);
        if (feat == 0) row[e].y = __float_as_int(nm);    // norm writeback
    }
    acc += __shfl_xor(acc, 4);   // reduce over slot bits (2,3)
    acc += __shfl_xor(acc, 8);
    if (slot == 0) agg1[n * 4 + feat] = acc;
}

// ---- y2[n,:] = relu(agg1[n,:] @ W1 + b1) @ W2, fp16 out, via MFMA -------
constexpr int HROW = 136;  // f16 units per node row in LDS
__global__ __launch_bounds__(256) void k_fused_l1(const float4* __restrict__ agg1,
                                                  const float* __restrict__ W1,
                                                  const float* __restrict__ b1,
                                                  const float* __restrict__ W2,
                                                  __half* __restrict__ y2h) {
    __shared__ _Float16 h1lds[4][16 * HROW];   // 4 waves x 4352 B = 17408 B
    int t = threadIdx.x, wave = t >> 6, lane = t & 63;
    int q = lane >> 4, c = lane & 15;
    _Float16* sh = h1lds[wave];

    int k1 = lane, k2 = lane + 64;
    float w10 = W1[0 * 128 + k1], w11 = W1[1 * 128 + k1];
    float w12 = W1[2 * 128 + k1], w13 = W1[3 * 128 + k1], bb1 = b1[k1];
    float w20 = W1[0 * 128 + k2], w21 = W1[1 * 128 + k2];
    float w22 = W1[2 * 128 + k2], w23 = W1[3 * 128 + k2], bb2 = b1[k2];

    f16x8 Bf[4][4];
#pragma unroll
    for (int kt = 0; kt < 4; kt++)
#pragma unroll
        for (int nt = 0; nt < 4; nt++)
#pragma unroll
            for (int j = 0; j < 8; j++)
                Bf[kt][nt][j] = (_Float16)W2[(kt * 32 + q * 8 + j) * 64 + nt * 16 + c];

    int wave_id = blockIdx.x * 4 + wave;
#pragma unroll
    for (int g = 0; g < 2; g++) {
        int n0 = (wave_id * 2 + g) * 16;
        if (n0 >= N) break;
#pragma unroll
        for (int m = 0; m < 16; m++) {
            float4 a = agg1[n0 + m];
            float v1 = bb1, v2 = bb2;
            v1 = fmaf(a.x, w10, v1); v1 = fmaf(a.y, w11, v1);
            v1 = fmaf(a.z, w12, v1); v1 = fmaf(a.w, w13, v1);
            v2 = fmaf(a.x, w20, v2); v2 = fmaf(a.y, w21, v2);
            v2 = fmaf(a.z, w22, v2); v2 = fmaf(a.w, w23, v2);
            sh[m * HROW + k1] = (_Float16)fmaxf(v1, 0.f);
            sh[m * HROW + k2] = (_Float16)fmaxf(v2, 0.f);
        }
        f32x4 C[4] = {{0.f, 0.f, 0.f, 0.f}, {0.f, 0.f, 0.f, 0.f},
                      {0.f, 0.f, 0.f, 0.f}, {0.f, 0.f, 0.f, 0.f}};
#pragma unroll
        for (int kt = 0; kt < 4; kt++) {
            f16x8 A = *(const f16x8*)&sh[c * HROW + kt * 32 + q * 8];
#pragma unroll
            for (int nt = 0; nt < 4; nt++)
                C[nt] = __builtin_amdgcn_mfma_f32_16x16x32_f16(A, Bf[kt][nt], C[nt], 0, 0, 0);
        }
#pragma unroll
        for (int nt = 0; nt < 4; nt++)
#pragma unroll
            for (int r = 0; r < 4; r++) {
                int node = n0 + q * 4 + r;
                y2h[(size_t)node * 64 + nt * 16 + c] = __float2half(C[nt][r]);
            }
    }
}

// ---- layer 2 aggregation + bias/relu + W3 dot: 4 nodes x 2 slots x 8 octets
__global__ __launch_bounds__(256) void k_agg2(const __half* __restrict__ y2h,
                                              const int* __restrict__ cursor,
                                              const int2* __restrict__ payload, int cap,
                                              const float* __restrict__ b2,
                                              const float* __restrict__ W3,
                                              float* __restrict__ s_out) {
    int t = threadIdx.x, lane = t & 63, wave = t >> 6;
    int nsub = lane >> 4, slot = (lane >> 3) & 1, k = lane & 7;
    int n = (blockIdx.x * 4 + wave) * 4 + nsub;   // grid exact
    float b2v[8], w3v[8];
#pragma unroll
    for (int j = 0; j < 8; j++) { b2v[j] = b2[k * 8 + j]; w3v[j] = W3[k * 8 + j]; }
    int cnt = cursor[n];
    const int2* row = payload + (size_t)n * cap;
    int iters = (cnt + 1) >> 1;
    float acc[8] = {0.f, 0.f, 0.f, 0.f, 0.f, 0.f, 0.f, 0.f};
    for (int it = 0; it < iters; it++) {
        int2 p = row[it * 2 + slot];
        float nm = __int_as_float(p.y);            // norm precomputed by k_agg1
        f16x8 v = *(const f16x8*)(y2h + (size_t)p.x * 64 + k * 8);
#pragma unroll
        for (int j = 0; j < 8; j++)
            acc[j] = fmaf(nm, (float)v[j], acc[j]);
    }
#pragma unroll
    for (int j = 0; j < 8; j++) acc[j] += __shfl_xor(acc[j], 8);  // slot reduce
    float p_ = 0.f;
#pragma unroll
    for (int j = 0; j < 8; j++) {
        float h = fmaxf(acc[j] + b2v[j], 0.f);
        p_ = fmaf(h, w3v[j], p_);
    }
    p_ += __shfl_xor(p_, 1);
    p_ += __shfl_xor(p_, 2);
    p_ += __shfl_xor(p_, 4);
    if (slot == 0 && k == 0) s_out[n] = p_;
}

// ---- layer 3 aggregation: 8 nodes x 8 slots per wave; out = acc + b3 -----
__global__ __launch_bounds__(256) void k_agg3(const float* __restrict__ s,
                                              const int* __restrict__ cursor,
                                              const int2* __restrict__ payload, int cap,
                                              const float* __restrict__ b3,
                                              float* __restrict__ out) {
    int t = threadIdx.x, lane = t & 63, wave = t >> 6;
    int nsub = lane >> 3, slot = lane & 7;
    int n = (blockIdx.x * 4 + wave) * 8 + nsub;   // grid exact: 3125*32 = N
    int cnt = cursor[n];
    const int2* row = payload + (size_t)n * cap;
    int iters = (cnt + 7) >> 3;
    float acc = 0.f;
    for (int it = 0; it < iters; it++) {
        int2 p = row[it * 8 + slot];
        acc = fmaf(__int_as_float(p.y), s[p.x], acc);  // pads: norm 0
    }
    acc += __shfl_xor(acc, 1);
    acc += __shfl_xor(acc, 2);
    acc += __shfl_xor(acc, 4);
    if (slot == 0) out[n] = acc + b3[0];
}

extern "C" void kernel_launch(void* const* d_in, const int* in_sizes, int n_in,
                              void* d_out, int out_size, void* d_ws, size_t ws_size,
                              hipStream_t stream) {
    const float* x  = (const float*)d_in[0];
    const int*   ei = (const int*)d_in[1];   // int32 (JAX x64-disabled)
    const int* src = ei;
    const int* dst = ei + E;
    const float* w  = (const float*)d_in[2];
    const float* W1 = (const float*)d_in[3];
    const float* b1 = (const float*)d_in[4];
    const float* W2 = (const float*)d_in[5];
    const float* b2 = (const float*)d_in[6];
    const float* W3 = (const float*)d_in[7];
    const float* b3 = (const float*)d_in[8];
    float* out = (float*)d_out;

    // layout: bcur[512] | cursor[N] | dis[N] | agg1[4N] | y2h[64N h] |
    //         sorted[NBKT*BCAP int2] | payload[N*cap int2]
    int*    bcur    = (int*)d_ws;
    int*    cursor  = bcur + 512;
    float*  dis     = (float*)(cursor + N);
    float*  agg1    = dis + N;
    __half* y2h     = (__half*)(agg1 + 4 * N);
    float*  s       = agg1;                     // agg1 dead after k_fused_l1
    int2*   sorted  = (int2*)((char*)y2h + (size_t)64 * N * sizeof(__half));
    int2*   payload = sorted + (size_t)NBKT * BCAP;
    size_t fixed_bytes = (size_t)(512 + 2 * N + 4 * N) * 4 + (size_t)64 * N * 2
                       + (size_t)NBKT * BCAP * 8;
    int cap = (int)((ws_size - fixed_bytes) / ((size_t)N * 8));
    if (cap > 64) cap = 64;   // multiple of 8; Poisson(8)+self max << 64

    k_zero    <<<cdiv(NBKT, 256), 256, 0, stream>>>(bcur);
    k_coarse  <<<GC,              256, 0, stream>>>(src, dst, w, bcur, sorted);
    k_fine    <<<NBKT,            256, 0, stream>>>(sorted, bcur, cap, payload, cursor, dis);
    k_agg1    <<<N / 16,          256, 0, stream>>>(x, dis, cursor, payload, cap, agg1);
    k_fused_l1<<<cdiv(N / 16, 8), 256, 0, stream>>>((const float4*)agg1, W1, b1, W2, y2h);
    k_agg2    <<<N / 16,          256, 0, stream>>>(y2h, cursor, payload, cap, b2, W3, s);
    k_agg3    <<<N / 32,          256, 0, stream>>>(s, cursor, payload, cap, b3, out);
}

// Round 9
// 163.726 us; speedup vs baseline: 3.8199x; 1.0375x over previous
//
#include <hip/hip_runtime.h>
#include <hip/hip_fp16.h>

// GCN 3-layer, N=100000 nodes, E=800000 edges, f32.
// out = A_hat @ (relu(A_hat @ (relu((A_hat @ x) @ W1 + b1)) @ W2 + b2) @ W3) + b3
// A_hat = D^-1/2 (A + I) D^-1/2, weighted, deg over dst.
//
// R6: fused_l1 on MFMA. R7: 2-phase bucket sort. R8: edge-parallel agg kernels,
//     norm computed once in agg1 and written back to payload.
// R9: k_coarse rebuilt as block-local LDS counting sort: hist -> LDS scan ->
//     sort 6400 records into LDS -> write per-bucket RUNS (mean 131B contiguous)
//     instead of 800k isolated random 8B stores (partial-line HBM amplification).
//     k_fine widened to 512 threads. (Harness d_ws poison = fixed 43us/iter.)

constexpr int N = 100000;
constexpr int E = 800000;
constexpr int NBKT = 391;    // buckets of 256 nodes
constexpr int BCAP = 3072;   // per-bucket capacity; mean 2046, ~22 sigma margin
constexpr int GC = 125;      // coarse blocks; 125 * 6400 = E exactly
constexpr int CHUNK = 6400;  // 25 full 256-thread iterations

static inline int cdiv(int a, int b) { return (a + b - 1) / b; }

typedef __attribute__((ext_vector_type(8))) _Float16 f16x8;
typedef __attribute__((ext_vector_type(4))) float f32x4;

__global__ void k_zero(int* __restrict__ bucket_cursor) {
    int i = blockIdx.x * blockDim.x + threadIdx.x;
    if (i < NBKT) bucket_cursor[i] = 0;
}

// coarse bucketing by dst>>8, block-local LDS counting sort, run-wise output.
// record = {src | (dst&255)<<17, bits(w)}
__global__ __launch_bounds__(256) void k_coarse(const int* __restrict__ src,
                                                const int* __restrict__ dst,
                                                const float* __restrict__ w,
                                                int* __restrict__ bucket_cursor,
                                                int2* __restrict__ sorted) {
    __shared__ int  hist[NBKT];     // per-bucket count, then kept for P5
    __shared__ int  lofs[512];      // scan workspace -> local exclusive offsets
    __shared__ int  gbase[NBKT];    // global base per bucket
    __shared__ int2 recs[CHUNK];    // 51.2 KB block-local sorted records
    int t = threadIdx.x;
    for (int i = t; i < NBKT; i += 256) hist[i] = 0;
    __syncthreads();
    int begin = blockIdx.x * CHUNK;
    int packed[25];                 // (rank<<17) | (bkt<<8) | dlo
#pragma unroll
    for (int i = 0; i < 25; i++) {
        int d = dst[begin + i * 256 + t];
        int b = d >> 8;
        int rank = atomicAdd(&hist[b], 1);
        packed[i] = (rank << 17) | (b << 8) | (d & 255);
    }
    __syncthreads();
    // P2: exclusive scan of hist[0..NBKT) via two independent 256-wide H-S scans
    int v0 = hist[t];
    int v1 = (256 + t < NBKT) ? hist[256 + t] : 0;
    lofs[t] = v0; lofs[256 + t] = v1;
    __syncthreads();
    for (int off = 1; off < 256; off <<= 1) {
        int u0 = (t >= off) ? lofs[t - off] : 0;
        int u1 = (t >= off) ? lofs[256 + t - off] : 0;
        __syncthreads();
        lofs[t] += u0; lofs[256 + t] += u1;
        __syncthreads();
    }
    int tot0 = lofs[255];
    lofs[t] -= v0;                       // inclusive -> exclusive
    lofs[256 + t] += tot0 - v1;
    __syncthreads();
    // P3: reserve global ranges (~391 atomics/block, 49k total)
    for (int i = t; i < NBKT; i += 256) {
        int h = hist[i];
        gbase[i] = h ? atomicAdd(&bucket_cursor[i], h) : 0;
    }
    __syncthreads();
    // P4: sort records into LDS (bucket-major)
#pragma unroll
    for (int i = 0; i < 25; i++) {
        int e = begin + i * 256 + t;
        int pk = packed[i];
        int b = (pk >> 8) & 511, rank = pk >> 17, dlo = pk & 255;
        recs[lofs[b] + rank] = make_int2(src[e] | (dlo << 17), __float_as_int(w[e]));
    }
    __syncthreads();
    // P5: per-bucket run copy — same-lane sequential 8B stores fill L2 lines
    for (int b = t; b < NBKT; b += 256) {
        int cnt = hist[b], lo = lofs[b], gb = gbase[b];
        int lim = BCAP - gb; if (cnt > lim) cnt = lim;
        int2* dstp = sorted + (size_t)b * BCAP + gb;
        for (int j = 0; j < cnt; j++) dstp[j] = recs[lo + j];
    }
}

// fine bucketing: one block per bucket, 512 threads. Slot 0 = self-loop {n,1.0};
// rows padded to x8 with {0, 0.0f}. Emits cursor/dis.
__global__ __launch_bounds__(512) void k_fine(const int2* __restrict__ sorted,
                                              const int* __restrict__ bucket_cursor,
                                              int cap, int2* __restrict__ payload,
                                              int* __restrict__ cursor,
                                              float* __restrict__ dis) {
    __shared__ int   ncnt[256];
    __shared__ float nwsum[256];
    int t = threadIdx.x, b = blockIdx.x;
    if (t < 256) { ncnt[t] = 1; nwsum[t] = 1.0f; }   // slot 0 = self-loop
    __syncthreads();
    int cnt = bucket_cursor[b]; if (cnt > BCAP) cnt = BCAP;
    const int2* seg = sorted + (size_t)b * BCAP;
    for (int i = t; i < cnt; i += 512) {
        int2 r = seg[i];
        int s = r.x & 0x1FFFF, dlo = r.x >> 17;
        int pos = atomicAdd(&ncnt[dlo], 1);
        atomicAdd(&nwsum[dlo], __int_as_float(r.y));
        if (pos < cap)
            payload[(size_t)(b * 256 + dlo) * cap + pos] = make_int2(s, r.y);
    }
    __syncthreads();
    int n = b * 256 + t;
    if (t < 256 && n < N) {
        int c = ncnt[t]; if (c > cap) c = cap;
        int2* row = payload + (size_t)n * cap;
        row[0] = make_int2(n, __float_as_int(1.0f));   // self-loop entry
        int cpad = (c + 7) & ~7;
        for (int e = c; e < cpad; e++) row[e] = make_int2(0, 0);
        cursor[n] = c;
        dis[n] = rsqrtf(nwsum[t]);
    }
}

// ---- layer 1 aggregation: 4 nodes x 4 edge-slots x 4 feats per wave ------
// Computes norm once per edge and writes it back into payload.y for agg2/agg3.
__global__ __launch_bounds__(256) void k_agg1(const float* __restrict__ x,
                                              const float* __restrict__ dis,
                                              const int* __restrict__ cursor,
                                              int2* __restrict__ payload, int cap,
                                              float* __restrict__ agg1) {
    int t = threadIdx.x, lane = t & 63, wave = t >> 6;
    int nsub = lane >> 4, slot = (lane >> 2) & 3, feat = lane & 3;
    int n = (blockIdx.x * 4 + wave) * 4 + nsub;   // grid exact: 6250*16 = N
    float di = dis[n];
    int cnt = cursor[n];
    int2* row = payload + (size_t)n * cap;
    int iters = (cnt + 3) >> 2;
    float acc = 0.f;
    for (int it = 0; it < iters; it++) {
        int e = it * 4 + slot;
        int2 p = row[e];
        float nm = dis[p.x] * __int_as_float(p.y) * di;  // self: di*1*di = di^2
        float xv = x[p.x * 4 + feat];
        acc = fmaf(nm, xv, acc);
        if (feat == 0) row[e].y = __float_as_int(nm);    // norm writeback
    }
    acc += __shfl_xor(acc, 4);
    acc += __shfl_xor(acc, 8);
    if (slot == 0) agg1[n * 4 + feat] = acc;
}

// ---- y2[n,:] = relu(agg1[n,:] @ W1 + b1) @ W2, fp16 out, via MFMA -------
constexpr int HROW = 136;  // f16 units per node row in LDS
__global__ __launch_bounds__(256) void k_fused_l1(const float4* __restrict__ agg1,
                                                  const float* __restrict__ W1,
                                                  const float* __restrict__ b1,
                                                  const float* __restrict__ W2,
                                                  __half* __restrict__ y2h) {
    __shared__ _Float16 h1lds[4][16 * HROW];   // 4 waves x 4352 B = 17408 B
    int t = threadIdx.x, wave = t >> 6, lane = t & 63;
    int q = lane >> 4, c = lane & 15;
    _Float16* sh = h1lds[wave];

    int k1 = lane, k2 = lane + 64;
    float w10 = W1[0 * 128 + k1], w11 = W1[1 * 128 + k1];
    float w12 = W1[2 * 128 + k1], w13 = W1[3 * 128 + k1], bb1 = b1[k1];
    float w20 = W1[0 * 128 + k2], w21 = W1[1 * 128 + k2];
    float w22 = W1[2 * 128 + k2], w23 = W1[3 * 128 + k2], bb2 = b1[k2];

    f16x8 Bf[4][4];
#pragma unroll
    for (int kt = 0; kt < 4; kt++)
#pragma unroll
        for (int nt = 0; nt < 4; nt++)
#pragma unroll
            for (int j = 0; j < 8; j++)
                Bf[kt][nt][j] = (_Float16)W2[(kt * 32 + q * 8 + j) * 64 + nt * 16 + c];

    int wave_id = blockIdx.x * 4 + wave;
#pragma unroll
    for (int g = 0; g < 2; g++) {
        int n0 = (wave_id * 2 + g) * 16;
        if (n0 >= N) break;
#pragma unroll
        for (int m = 0; m < 16; m++) {
            float4 a = agg1[n0 + m];
            float v1 = bb1, v2 = bb2;
            v1 = fmaf(a.x, w10, v1); v1 = fmaf(a.y, w11, v1);
            v1 = fmaf(a.z, w12, v1); v1 = fmaf(a.w, w13, v1);
            v2 = fmaf(a.x, w20, v2); v2 = fmaf(a.y, w21, v2);
            v2 = fmaf(a.z, w22, v2); v2 = fmaf(a.w, w23, v2);
            sh[m * HROW + k1] = (_Float16)fmaxf(v1, 0.f);
            sh[m * HROW + k2] = (_Float16)fmaxf(v2, 0.f);
        }
        f32x4 C[4] = {{0.f, 0.f, 0.f, 0.f}, {0.f, 0.f, 0.f, 0.f},
                      {0.f, 0.f, 0.f, 0.f}, {0.f, 0.f, 0.f, 0.f}};
#pragma unroll
        for (int kt = 0; kt < 4; kt++) {
            f16x8 A = *(const f16x8*)&sh[c * HROW + kt * 32 + q * 8];
#pragma unroll
            for (int nt = 0; nt < 4; nt++)
                C[nt] = __builtin_amdgcn_mfma_f32_16x16x32_f16(A, Bf[kt][nt], C[nt], 0, 0, 0);
        }
#pragma unroll
        for (int nt = 0; nt < 4; nt++)
#pragma unroll
            for (int r = 0; r < 4; r++) {
                int node = n0 + q * 4 + r;
                y2h[(size_t)node * 64 + nt * 16 + c] = __float2half(C[nt][r]);
            }
    }
}

// ---- layer 2 aggregation + bias/relu + W3 dot: 4 nodes x 2 slots x 8 octets
__global__ __launch_bounds__(256) void k_agg2(const __half* __restrict__ y2h,
                                              const int* __restrict__ cursor,
                                              const int2* __restrict__ payload, int cap,
                                              const float* __restrict__ b2,
                                              const float* __restrict__ W3,
                                              float* __restrict__ s_out) {
    int t = threadIdx.x, lane = t & 63, wave = t >> 6;
    int nsub = lane >> 4, slot = (lane >> 3) & 1, k = lane & 7;
    int n = (blockIdx.x * 4 + wave) * 4 + nsub;
    float b2v[8], w3v[8];
#pragma unroll
    for (int j = 0; j < 8; j++) { b2v[j] = b2[k * 8 + j]; w3v[j] = W3[k * 8 + j]; }
    int cnt = cursor[n];
    const int2* row = payload + (size_t)n * cap;
    int iters = (cnt + 1) >> 1;
    float acc[8] = {0.f, 0.f, 0.f, 0.f, 0.f, 0.f, 0.f, 0.f};
    for (int it = 0; it < iters; it++) {
        int2 p = row[it * 2 + slot];
        float nm = __int_as_float(p.y);            // norm precomputed by k_agg1
        f16x8 v = *(const f16x8*)(y2h + (size_t)p.x * 64 + k * 8);
#pragma unroll
        for (int j = 0; j < 8; j++)
            acc[j] = fmaf(nm, (float)v[j], acc[j]);
    }
#pragma unroll
    for (int j = 0; j < 8; j++) acc[j] += __shfl_xor(acc[j], 8);
    float p_ = 0.f;
#pragma unroll
    for (int j = 0; j < 8; j++) {
        float h = fmaxf(acc[j] + b2v[j], 0.f);
        p_ = fmaf(h, w3v[j], p_);
    }
    p_ += __shfl_xor(p_, 1);
    p_ += __shfl_xor(p_, 2);
    p_ += __shfl_xor(p_, 4);
    if (slot == 0 && k == 0) s_out[n] = p_;
}

// ---- layer 3 aggregation: 8 nodes x 8 slots per wave; out = acc + b3 -----
__global__ __launch_bounds__(256) void k_agg3(const float* __restrict__ s,
                                              const int* __restrict__ cursor,
                                              const int2* __restrict__ payload, int cap,
                                              const float* __restrict__ b3,
                                              float* __restrict__ out) {
    int t = threadIdx.x, lane = t & 63, wave = t >> 6;
    int nsub = lane >> 3, slot = lane & 7;
    int n = (blockIdx.x * 4 + wave) * 8 + nsub;
    int cnt = cursor[n];
    const int2* row = payload + (size_t)n * cap;
    int iters = (cnt + 7) >> 3;
    float acc = 0.f;
    for (int it = 0; it < iters; it++) {
        int2 p = row[it * 8 + slot];
        acc = fmaf(__int_as_float(p.y), s[p.x], acc);  // pads: norm 0
    }
    acc += __shfl_xor(acc, 1);
    acc += __shfl_xor(acc, 2);
    acc += __shfl_xor(acc, 4);
    if (slot == 0) out[n] = acc + b3[0];
}

extern "C" void kernel_launch(void* const* d_in, const int* in_sizes, int n_in,
                              void* d_out, int out_size, void* d_ws, size_t ws_size,
                              hipStream_t stream) {
    const float* x  = (const float*)d_in[0];
    const int*   ei = (const int*)d_in[1];   // int32 (JAX x64-disabled)
    const int* src = ei;
    const int* dst = ei + E;
    const float* w  = (const float*)d_in[2];
    const float* W1 = (const float*)d_in[3];
    const float* b1 = (const float*)d_in[4];
    const float* W2 = (const float*)d_in[5];
    const float* b2 = (const float*)d_in[6];
    const float* W3 = (const float*)d_in[7];
    const float* b3 = (const float*)d_in[8];
    float* out = (float*)d_out;

    // layout: bcur[512] | cursor[N] | dis[N] | agg1[4N] | y2h[64N h] |
    //         sorted[NBKT*BCAP int2] | payload[N*cap int2]
    int*    bcur    = (int*)d_ws;
    int*    cursor  = bcur + 512;
    float*  dis     = (float*)(cursor + N);
    float*  agg1    = dis + N;
    __half* y2h     = (__half*)(agg1 + 4 * N);
    float*  s       = agg1;                     // agg1 dead after k_fused_l1
    int2*   sorted  = (int2*)((char*)y2h + (size_t)64 * N * sizeof(__half));
    int2*   payload = sorted + (size_t)NBKT * BCAP;
    size_t fixed_bytes = (size_t)(512 + 2 * N + 4 * N) * 4 + (size_t)64 * N * 2
                       + (size_t)NBKT * BCAP * 8;
    int cap = (int)((ws_size - fixed_bytes) / ((size_t)N * 8));
    if (cap > 64) cap = 64;   // multiple of 8; Poisson(8)+self max << 64

    k_zero    <<<cdiv(NBKT, 256), 256, 0, stream>>>(bcur);
    k_coarse  <<<GC,              256, 0, stream>>>(src, dst, w, bcur, sorted);
    k_fine    <<<NBKT,            512, 0, stream>>>(sorted, bcur, cap, payload, cursor, dis);
    k_agg1    <<<N / 16,          256, 0, stream>>>(x, dis, cursor, payload, cap, agg1);
    k_fused_l1<<<cdiv(N / 16, 8), 256, 0, stream>>>((const float4*)agg1, W1, b1, W2, y2h);
    k_agg2    <<<N / 16,          256, 0, stream>>>(y2h, cursor, payload, cap, b2, W3, s);
    k_agg3    <<<N / 32,          256, 0, stream>>>(s, cursor, payload, cap, b3, out);
}